// Round 2
// baseline (2124.777 us; speedup 1.0000x reference)
//
#include <hip/hip_runtime.h>

// ---------------------------------------------------------------------------
// TNO-v2 forward, fp32 compute with bf16 intermediates.
// Workspace budget: 192 MB (regions reused by liveness):
//   [0,64MB)    XN fp32  -> (after u/v proj) D0|D1|ASPEC|TW -> CT bf16 over D0/D1
//   [64,128MB)  VT fp32  -> (after conv) G bf16
//   [128,192MB) U bf16
// ---------------------------------------------------------------------------

#define FFTN 8192
#define SWZ(p) ((p) ^ (((p) >> 8) & 31))

typedef unsigned short u16;
typedef unsigned int u32;

__device__ __forceinline__ int brev13(int x) { return (int)(__brev((unsigned)x) >> 19); }
__device__ __forceinline__ float b2f(u16 u) {
  union { float f; u32 i; } c; c.i = ((u32)u) << 16; return c.f;
}
__device__ __forceinline__ u16 f2b(float f) {
  union { float f; u32 i; } c; c.f = f;
  u32 r = c.i + 0x7FFFu + ((c.i >> 16) & 1u);
  return (u16)(r >> 16);
}
__device__ __forceinline__ float silu_f(float x) { return x / (1.f + __expf(-x)); }

// ---------------- twiddles: tw[k] = exp(-2*pi*i*k/8192), k<4096 -------------
__global__ void twiddle_init_kernel(float2* __restrict__ tw) {
  int k = blockIdx.x * blockDim.x + threadIdx.x;
  if (k < 4096) {
    double ang = -6.283185307179586476925286766559 * ((double)k / 8192.0);
    tw[k] = make_float2((float)cos(ang), (float)sin(ang));
  }
}

// ---------------- SimpleRMSNorm over rows of 512 (optional relu) ------------
__global__ __launch_bounds__(256) void srms_kernel(
    const float* __restrict__ in, float* __restrict__ out, int rows, int do_relu)
{
  int wave = threadIdx.x >> 6, lane = threadIdx.x & 63;
  int row = (blockIdx.x << 2) + wave;
  if (row >= rows) return;
  const float4* p = (const float4*)(in + (size_t)row * 512);
  float4 a = p[lane], b = p[lane + 64];
  float ss = a.x*a.x + a.y*a.y + a.z*a.z + a.w*a.w
           + b.x*b.x + b.y*b.y + b.z*b.z + b.w*b.w;
#pragma unroll
  for (int off = 32; off > 0; off >>= 1) ss += __shfl_xor(ss, off);
  float inv = 1.0f / (sqrtf(ss) * 0.04419417382415922f + 1e-8f);
  a.x *= inv; a.y *= inv; a.z *= inv; a.w *= inv;
  b.x *= inv; b.y *= inv; b.z *= inv; b.w *= inv;
  if (do_relu) {
    a.x = fmaxf(a.x, 0.f); a.y = fmaxf(a.y, 0.f); a.z = fmaxf(a.z, 0.f); a.w = fmaxf(a.w, 0.f);
    b.x = fmaxf(b.x, 0.f); b.y = fmaxf(b.y, 0.f); b.z = fmaxf(b.z, 0.f); b.w = fmaxf(b.w, 0.f);
  }
  float4* o = (float4*)(out + (size_t)row * 512);
  o[lane] = a; o[lane + 64] = b;
}

// ---------------- DPB layer 0: relu(srms(p*Wp + bp)) for 8192 positions -----
__global__ __launch_bounds__(256) void dpb0_kernel(
    const float* __restrict__ Wp, const float* __restrict__ bp, float* __restrict__ out)
{
  int wave = threadIdx.x >> 6, lane = threadIdx.x & 63;
  int row = (blockIdx.x << 2) + wave;   // circulant index 0..8191
  if (row >= 8192) return;
  float pv;
  if (row == 0 || row == 4096) pv = 0.f;
  else if (row < 4096) pv = (float)row;
  else pv = (float)(row - 8192);
  const float4* wp  = (const float4*)Wp;
  const float4* bpp = (const float4*)bp;
  float4 a = wp[lane], b = wp[lane + 64];
  float4 c = bpp[lane], d = bpp[lane + 64];
  a.x = fmaf(pv, a.x, c.x); a.y = fmaf(pv, a.y, c.y);
  a.z = fmaf(pv, a.z, c.z); a.w = fmaf(pv, a.w, c.w);
  b.x = fmaf(pv, b.x, d.x); b.y = fmaf(pv, b.y, d.y);
  b.z = fmaf(pv, b.z, d.z); b.w = fmaf(pv, b.w, d.w);
  float ss = a.x*a.x + a.y*a.y + a.z*a.z + a.w*a.w
           + b.x*b.x + b.y*b.y + b.z*b.z + b.w*b.w;
#pragma unroll
  for (int off = 32; off > 0; off >>= 1) ss += __shfl_xor(ss, off);
  float inv = 1.0f / (sqrtf(ss) * 0.04419417382415922f + 1e-8f);
  a.x = fmaxf(a.x * inv, 0.f); a.y = fmaxf(a.y * inv, 0.f);
  a.z = fmaxf(a.z * inv, 0.f); a.w = fmaxf(a.w * inv, 0.f);
  b.x = fmaxf(b.x * inv, 0.f); b.y = fmaxf(b.y * inv, 0.f);
  b.z = fmaxf(b.z * inv, 0.f); b.w = fmaxf(b.w * inv, 0.f);
  float4* o = (float4*)(out + (size_t)row * 512);
  o[lane] = a; o[lane + 64] = b;
}

// ---------------- shared GEMM inner product (64x64 tile, 4x4/thread) --------
__device__ __forceinline__ void mm_inner(const float (*As)[64], const float (*Bs)[64],
                                         int tx, int ty, float acc[4][4])
{
#pragma unroll
  for (int kk = 0; kk < 16; kk++) {
    const float4 a4 = *(const float4*)(&As[kk][ty << 2]);
    const float4 b4 = *(const float4*)(&Bs[kk][tx << 2]);
    acc[0][0] = fmaf(a4.x, b4.x, acc[0][0]);
    acc[0][1] = fmaf(a4.x, b4.y, acc[0][1]);
    acc[0][2] = fmaf(a4.x, b4.z, acc[0][2]);
    acc[0][3] = fmaf(a4.x, b4.w, acc[0][3]);
    acc[1][0] = fmaf(a4.y, b4.x, acc[1][0]);
    acc[1][1] = fmaf(a4.y, b4.y, acc[1][1]);
    acc[1][2] = fmaf(a4.y, b4.z, acc[1][2]);
    acc[1][3] = fmaf(a4.y, b4.w, acc[1][3]);
    acc[2][0] = fmaf(a4.z, b4.x, acc[2][0]);
    acc[2][1] = fmaf(a4.z, b4.y, acc[2][1]);
    acc[2][2] = fmaf(a4.z, b4.z, acc[2][2]);
    acc[2][3] = fmaf(a4.z, b4.w, acc[2][3]);
    acc[3][0] = fmaf(a4.w, b4.x, acc[3][0]);
    acc[3][1] = fmaf(a4.w, b4.y, acc[3][1]);
    acc[3][2] = fmaf(a4.w, b4.z, acc[3][2]);
    acc[3][3] = fmaf(a4.w, b4.w, acc[3][3]);
  }
}

// ---------------- GEMM variant A: fp32 A rm -> fp32 C rm, + bias ------------
__global__ __launch_bounds__(256) void gemm_a32_kernel(
    const float* __restrict__ A, const float* __restrict__ B,
    const float* __restrict__ bias, float* __restrict__ C, int M, int N, int K)
{
  __shared__ float As[16][64], Bs[16][64];
  const int bm = blockIdx.y << 6, bn = blockIdx.x << 6;
  const int tid = threadIdx.x, tx = tid & 15, ty = tid >> 4;
  const int am = tid >> 2, ak = (tid & 3) << 2;
  const int bk = tid >> 4, bn4 = (tid & 15) << 2;
  const float* Ap = A + (size_t)(bm + am) * K + ak;
  const float* Bp = B + (size_t)bk * N + bn + bn4;
  float acc[4][4] = {};
  for (int k0 = 0; k0 < K; k0 += 16) {
    const float4 av = *(const float4*)Ap;
    const float4 bv = *(const float4*)Bp;
    Ap += 16; Bp += (size_t)16 * N;
    __syncthreads();
    As[ak + 0][am] = av.x; As[ak + 1][am] = av.y;
    As[ak + 2][am] = av.z; As[ak + 3][am] = av.w;
    *(float4*)(&Bs[bk][bn4]) = bv;
    __syncthreads();
    mm_inner(As, Bs, tx, ty, acc);
  }
  const int ncol = bn + (tx << 2);
  const float4 bi = *(const float4*)(bias + ncol);
#pragma unroll
  for (int i = 0; i < 4; i++) {
    const int m = bm + (ty << 2) + i;
    float4 v = make_float4(acc[i][0] + bi.x, acc[i][1] + bi.y,
                           acc[i][2] + bi.z, acc[i][3] + bi.w);
    *(float4*)(C + (size_t)m * N + ncol) = v;
  }
}

// ---------------- GEMM variant VT: silu, store transposed fp32 (b,c,j) ------
__global__ __launch_bounds__(256) void gemm_vt_kernel(
    const float* __restrict__ A, const float* __restrict__ B,
    const float* __restrict__ bias, float* __restrict__ VT, int M, int N, int K)
{
  __shared__ float As[16][64], Bs[16][64];
  const int bm = blockIdx.y << 6, bn = blockIdx.x << 6;
  const int tid = threadIdx.x, tx = tid & 15, ty = tid >> 4;
  const int am = tid >> 2, ak = (tid & 3) << 2;
  const int bk = tid >> 4, bn4 = (tid & 15) << 2;
  const float* Ap = A + (size_t)(bm + am) * K + ak;
  const float* Bp = B + (size_t)bk * N + bn + bn4;
  float acc[4][4] = {};
  for (int k0 = 0; k0 < K; k0 += 16) {
    const float4 av = *(const float4*)Ap;
    const float4 bv = *(const float4*)Bp;
    Ap += 16; Bp += (size_t)16 * N;
    __syncthreads();
    As[ak + 0][am] = av.x; As[ak + 1][am] = av.y;
    As[ak + 2][am] = av.z; As[ak + 3][am] = av.w;
    *(float4*)(&Bs[bk][bn4]) = bv;
    __syncthreads();
    mm_inner(As, Bs, tx, ty, acc);
  }
  // transposed epilogue: m = b*4096 + j ; store VT[(b*512+c)*4096 + j]
  const int ncol = bn + (tx << 2);
  const int b = bm >> 12;
  const int j0 = (bm & 4095) + (ty << 2);
#pragma unroll
  for (int jj = 0; jj < 4; jj++) {
    const int c = ncol + jj;
    const float bi = bias[c];
    float4 v = make_float4(silu_f(acc[0][jj] + bi), silu_f(acc[1][jj] + bi),
                           silu_f(acc[2][jj] + bi), silu_f(acc[3][jj] + bi));
    *(float4*)(VT + (((size_t)(b * 512 + c)) << 12) + j0) = v;
  }
}

// ---------------- GEMM variant U: silu, store bf16 rm -----------------------
__global__ __launch_bounds__(256) void gemm_u_kernel(
    const float* __restrict__ A, const float* __restrict__ B,
    const float* __restrict__ bias, u16* __restrict__ C, int M, int N, int K)
{
  __shared__ float As[16][64], Bs[16][64];
  const int bm = blockIdx.y << 6, bn = blockIdx.x << 6;
  const int tid = threadIdx.x, tx = tid & 15, ty = tid >> 4;
  const int am = tid >> 2, ak = (tid & 3) << 2;
  const int bk = tid >> 4, bn4 = (tid & 15) << 2;
  const float* Ap = A + (size_t)(bm + am) * K + ak;
  const float* Bp = B + (size_t)bk * N + bn + bn4;
  float acc[4][4] = {};
  for (int k0 = 0; k0 < K; k0 += 16) {
    const float4 av = *(const float4*)Ap;
    const float4 bv = *(const float4*)Bp;
    Ap += 16; Bp += (size_t)16 * N;
    __syncthreads();
    As[ak + 0][am] = av.x; As[ak + 1][am] = av.y;
    As[ak + 2][am] = av.z; As[ak + 3][am] = av.w;
    *(float4*)(&Bs[bk][bn4]) = bv;
    __syncthreads();
    mm_inner(As, Bs, tx, ty, acc);
  }
  const int ncol = bn + (tx << 2);
  const float4 bi = *(const float4*)(bias + ncol);
#pragma unroll
  for (int i = 0; i < 4; i++) {
    const int m = bm + (ty << 2) + i;
    ushort4 s;
    s.x = f2b(silu_f(acc[i][0] + bi.x));
    s.y = f2b(silu_f(acc[i][1] + bi.y));
    s.z = f2b(silu_f(acc[i][2] + bi.z));
    s.w = f2b(silu_f(acc[i][3] + bi.w));
    *(ushort4*)(C + (size_t)m * N + ncol) = s;
  }
}

// ---------------- GEMM variant gate: A bf16 k-major (b,c,j), * U, bf16 out --
__global__ __launch_bounds__(256) void gemm_gate_kernel(
    const u16* __restrict__ Akm, const float* __restrict__ B,
    const float* __restrict__ bias, const u16* __restrict__ Ug,
    u16* __restrict__ G, int M, int N, int K)
{
  __shared__ float As[16][64], Bs[16][64];
  const int bm = blockIdx.y << 6, bn = blockIdx.x << 6;
  const int tid = threadIdx.x, tx = tid & 15, ty = tid >> 4;
  const int bk = tid >> 4;           // k-row 0..15
  const int bm4 = (tid & 15) << 2;   // m offset 0..60
  const int bbase = (bm >> 12) * 512;
  const int j0 = bm & 4095;
  const u16* Ap = Akm + (((size_t)(bbase + bk)) << 12) + j0 + bm4;
  const float* Bp = B + (size_t)bk * N + bn + bm4;
  float acc[4][4] = {};
  for (int k0 = 0; k0 < K; k0 += 16) {
    const ushort4 au = *(const ushort4*)Ap;
    const float4 bv = *(const float4*)Bp;
    Ap += ((size_t)16) << 12;   // +16 k rows of 4096
    Bp += (size_t)16 * N;
    __syncthreads();
    As[bk][bm4 + 0] = b2f(au.x); As[bk][bm4 + 1] = b2f(au.y);
    As[bk][bm4 + 2] = b2f(au.z); As[bk][bm4 + 3] = b2f(au.w);
    *(float4*)(&Bs[bk][bm4]) = bv;
    __syncthreads();
    mm_inner(As, Bs, tx, ty, acc);
  }
  const int ncol = bn + (tx << 2);
  const float4 bi = *(const float4*)(bias + ncol);
#pragma unroll
  for (int i = 0; i < 4; i++) {
    const int m = bm + (ty << 2) + i;
    const size_t idx = (size_t)m * N + ncol;
    const ushort4 g = *(const ushort4*)(Ug + idx);
    ushort4 s;
    s.x = f2b((acc[i][0] + bi.x) * b2f(g.x));
    s.y = f2b((acc[i][1] + bi.y) * b2f(g.y));
    s.z = f2b((acc[i][2] + bi.z) * b2f(g.z));
    s.w = f2b((acc[i][3] + bi.w) * b2f(g.w));
    *(ushort4*)(G + idx) = s;
  }
}

// ---------------- GEMM variant final: A bf16 rm, + bias + resid, fp32 out ---
__global__ __launch_bounds__(256) void gemm_final_kernel(
    const u16* __restrict__ A, const float* __restrict__ B,
    const float* __restrict__ bias, const float* __restrict__ resid,
    float* __restrict__ C, int M, int N, int K)
{
  __shared__ float As[16][64], Bs[16][64];
  const int bm = blockIdx.y << 6, bn = blockIdx.x << 6;
  const int tid = threadIdx.x, tx = tid & 15, ty = tid >> 4;
  const int am = tid >> 2, ak = (tid & 3) << 2;
  const int bk = tid >> 4, bn4 = (tid & 15) << 2;
  const u16* Ap = A + (size_t)(bm + am) * K + ak;
  const float* Bp = B + (size_t)bk * N + bn + bn4;
  float acc[4][4] = {};
  for (int k0 = 0; k0 < K; k0 += 16) {
    const ushort4 au = *(const ushort4*)Ap;
    const float4 bv = *(const float4*)Bp;
    Ap += 16; Bp += (size_t)16 * N;
    __syncthreads();
    As[ak + 0][am] = b2f(au.x); As[ak + 1][am] = b2f(au.y);
    As[ak + 2][am] = b2f(au.z); As[ak + 3][am] = b2f(au.w);
    *(float4*)(&Bs[bk][bn4]) = bv;
    __syncthreads();
    mm_inner(As, Bs, tx, ty, acc);
  }
  const int ncol = bn + (tx << 2);
  const float4 bi = *(const float4*)(bias + ncol);
#pragma unroll
  for (int i = 0; i < 4; i++) {
    const int m = bm + (ty << 2) + i;
    const size_t idx = (size_t)m * N + ncol;
    const float4 r = *(const float4*)(resid + idx);
    float4 v = make_float4(acc[i][0] + bi.x + r.x, acc[i][1] + bi.y + r.y,
                           acc[i][2] + bi.z + r.z, acc[i][3] + bi.w + r.w);
    *(float4*)(C + idx) = v;
  }
}

// ---------------- in-LDS 8192-pt FFT (512 threads) --------------------------
__device__ __forceinline__ void fft8192_dit(float* sr, float* si,
                                            const float2* __restrict__ tw)
{
  const int t = threadIdx.x;
  for (int s = 0; s < 13; s++) {
    __syncthreads();
    const int half = 1 << s;
#pragma unroll
    for (int bb = 0; bb < 8; bb++) {
      const int u = t + (bb << 9);
      const int j = u & (half - 1);
      const int i0 = ((u >> s) << (s + 1)) | j;
      const int i1 = i0 + half;
      const float2 w = tw[j << (12 - s)];
      const int p0 = SWZ(i0), p1 = SWZ(i1);
      const float br = sr[p1], bi = si[p1];
      const float tr = br * w.x - bi * w.y;
      const float ti = br * w.y + bi * w.x;
      const float ar = sr[p0], ai = si[p0];
      sr[p0] = ar + tr; si[p0] = ai + ti;
      sr[p1] = ar - tr; si[p1] = ai - ti;
    }
  }
  __syncthreads();
}

__device__ __forceinline__ void ifft8192_dif(float* sr, float* si,
                                             const float2* __restrict__ tw)
{
  const int t = threadIdx.x;
  for (int s = 12; s >= 0; s--) {
    __syncthreads();
    const int half = 1 << s;
#pragma unroll
    for (int bb = 0; bb < 8; bb++) {
      const int u = t + (bb << 9);
      const int j = u & (half - 1);
      const int i0 = ((u >> s) << (s + 1)) | j;
      const int i1 = i0 + half;
      const float2 w = tw[j << (12 - s)];  // conj applied below
      const int p0 = SWZ(i0), p1 = SWZ(i1);
      const float ar = sr[p0], ai = si[p0];
      const float br = sr[p1], bi = si[p1];
      const float dr = ar - br, di = ai - bi;
      sr[p0] = ar + br; si[p0] = ai + bi;
      sr[p1] = dr * w.x + di * w.y;
      si[p1] = di * w.x - dr * w.y;
    }
  }
  __syncthreads();
}

// ---------------- kernel spectra ---------------------------------------------
__global__ __launch_bounds__(512) void kfft_kernel(
    const float* __restrict__ atab, const float2* __restrict__ tw,
    float2* __restrict__ aspec)
{
  __shared__ float sr[FFTN];
  __shared__ float si[FFTN];
  const int q = blockIdx.x;
  const int t = threadIdx.x;
#pragma unroll
  for (int it = 0; it < 16; it++) {
    const int r = t + (it << 9);
    const float2 v = *(const float2*)(atab + (size_t)r * 512 + 2 * q);
    const int d = SWZ(brev13(r));
    sr[d] = v.x; si[d] = v.y;
  }
  fft8192_dit(sr, si, tw);
  float2* O0 = aspec + (size_t)(2 * q) * 4097;
  float2* O1 = aspec + (size_t)(2 * q + 1) * 4097;
#pragma unroll 1
  for (int it = 0; it < 8; it++) {
    const int k = t + (it << 9);
    const int k2 = (FFTN - k) & (FFTN - 1);
    const float zr = sr[SWZ(k)],  zi = si[SWZ(k)];
    const float wr = sr[SWZ(k2)], wi = si[SWZ(k2)];
    O0[k] = make_float2(0.5f * (zr + wr), 0.5f * (zi - wi));
    O1[k] = make_float2(0.5f * (zi + wi), 0.5f * (wr - zr));
  }
  if (t == 0) {
    const float zr = sr[SWZ(4096)], zi = si[SWZ(4096)];
    O0[4096] = make_float2(zr, 0.f);
    O1[4096] = make_float2(zi, 0.f);
  }
}

// ---------------- pointwise spectral multiply (fixed self-conjugate bins) ---
__device__ __forceinline__ void mulpoint(float* sr, float* si,
    const float2* __restrict__ A0, const float2* __restrict__ A1, int k)
{
  const int k2 = (FFTN - k) & (FFTN - 1);
  const int pk = SWZ(k), pk2 = SWZ(k2);
  const float zr = sr[pk],  zi = si[pk];
  const float wr = sr[pk2], wi = si[pk2];
  const float Xr = 0.5f * (zr + wr), Xi = 0.5f * (zi - wi);
  const float Yr = 0.5f * (zi + wi), Yi = 0.5f * (wr - zr);
  const float2 a0 = A0[k], a1 = A1[k];
  const float Pr = Xr * a0.x - Xi * a0.y, Pi = Xr * a0.y + Xi * a0.x;
  const float Qr = Yr * a1.x - Yi * a1.y, Qi = Yr * a1.y + Yi * a1.x;
  sr[pk]  = Pr - Qi;  si[pk]  = Pi + Qr;
  if (k2 != k) {            // k=0 / k=4096 are self-conjugate: single write
    sr[pk2] = Pr + Qi;  si[pk2] = Qr - Pi;
  }
}

__global__ __launch_bounds__(512) void conv_kernel(
    const float* __restrict__ vT,     // (8, 512, 4096) fp32
    const float2* __restrict__ aspec, // (512, 4097)
    const float2* __restrict__ tw,
    u16* __restrict__ outT)           // (8, 512, 4096) bf16
{
  __shared__ float sr[FFTN];
  __shared__ float si[FFTN];
  const int q = blockIdx.x;
  const int b = blockIdx.y;
  const int c0 = 2 * q, c1 = 2 * q + 1;
  const int t = threadIdx.x;
  const float* p0 = vT + ((size_t)b * 512 + c0) * 4096;
  const float* p1 = vT + ((size_t)b * 512 + c1) * 4096;
#pragma unroll
  for (int it = 0; it < 16; it++) {
    const int j = t + (it << 9);
    float a = 0.f, bb = 0.f;
    if (j < 4096) { a = p0[j]; bb = p1[j]; }
    const int d = SWZ(brev13(j));
    sr[d] = a; si[d] = bb;
  }
  fft8192_dit(sr, si, tw);
  const float2* A0 = aspec + (size_t)c0 * 4097;
  const float2* A1 = aspec + (size_t)c1 * 4097;
#pragma unroll 1
  for (int it = 0; it < 8; it++) {
    mulpoint(sr, si, A0, A1, t + (it << 9));
  }
  if (t == 0) mulpoint(sr, si, A0, A1, 4096);
  ifft8192_dif(sr, si, tw);
  const float scale = 1.0f / 8192.0f;
  u16* o0 = outT + ((size_t)b * 512 + c0) * 4096;
  u16* o1 = outT + ((size_t)b * 512 + c1) * 4096;
#pragma unroll
  for (int it = 0; it < 8; it++) {
    const int i = t + (it << 9);
    const int d = SWZ(brev13(i));
    o0[i] = f2b(sr[d] * scale);
    o1[i] = f2b(si[d] * scale);
  }
}

// ---------------------------------------------------------------------------
extern "C" void kernel_launch(void* const* d_in, const int* in_sizes, int n_in,
                              void* d_out, int out_size, void* d_ws, size_t ws_size,
                              hipStream_t stream)
{
  const float* x   = (const float*)d_in[0];
  const float* Wu  = (const float*)d_in[1];
  const float* bu  = (const float*)d_in[2];
  const float* Wv  = (const float*)d_in[3];
  const float* bv  = (const float*)d_in[4];
  const float* Wo1 = (const float*)d_in[5];
  const float* bo1 = (const float*)d_in[6];
  const float* Wo2 = (const float*)d_in[7];
  const float* bo2 = (const float*)d_in[8];
  const float* dWp = (const float*)d_in[9];
  const float* dbp = (const float*)d_in[10];
  const float* dW1 = (const float*)d_in[11];
  const float* db1 = (const float*)d_in[12];
  const float* dW2 = (const float*)d_in[13];
  const float* db2 = (const float*)d_in[14];
  const float* dW3 = (const float*)d_in[15];
  const float* db3 = (const float*)d_in[16];
  float* out = (float*)d_out;

  char* wsb = (char*)d_ws;
  const size_t MB = 1u << 20;
  // region 0: [0, 64MB)
  float*  XN    = (float*)wsb;                 // 32768x512 fp32 (dies after u-proj)
  float*  D0    = (float*)wsb;                 // 8192x512 fp32
  float*  D1    = (float*)(wsb + 16 * MB);     // 8192x512 fp32
  float2* ASPEC = (float2*)(wsb + 32 * MB);    // 512x4097 c64 (~16MB)
  float2* TW    = (float2*)(wsb + 50 * MB);    // 4096 c64
  u16*    CT    = (u16*)wsb;                   // (8,512,4096) bf16 over D0/D1
  // region 1: [64MB, 128MB)
  float*  VT    = (float*)(wsb + 64 * MB);     // (8,512,4096) fp32 (dies after conv)
  u16*    G     = (u16*)(wsb + 64 * MB);       // 32768x1024 bf16
  // region 2: [128MB, 192MB)
  u16*    U     = (u16*)(wsb + 128 * MB);      // 32768x1024 bf16

  // pre-norm
  srms_kernel<<<8192, 256, 0, stream>>>(x, XN, 32768, 0);
  // v = silu(xn@Wv + bv) -> VT channel-major (fused transpose)
  gemm_vt_kernel<<<dim3(8, 512), 256, 0, stream>>>(XN, Wv, bv, VT, 32768, 512, 512);
  // u = silu(xn@Wu + bu) -> U bf16 (XN dead after this)
  gemm_u_kernel<<<dim3(16, 512), 256, 0, stream>>>(XN, Wu, bu, U, 32768, 1024, 512);
  // twiddles (after XN dies; TW lives inside region 0)
  twiddle_init_kernel<<<8, 512, 0, stream>>>(TW);
  // DPB MLP -> circulant table D1 (8192, 512)
  dpb0_kernel<<<2048, 256, 0, stream>>>(dWp, dbp, D0);
  gemm_a32_kernel<<<dim3(8, 128), 256, 0, stream>>>(D0, dW1, db1, D1, 8192, 512, 512);
  srms_kernel<<<2048, 256, 0, stream>>>(D1, D0, 8192, 1);
  gemm_a32_kernel<<<dim3(8, 128), 256, 0, stream>>>(D0, dW2, db2, D1, 8192, 512, 512);
  srms_kernel<<<2048, 256, 0, stream>>>(D1, D0, 8192, 1);
  gemm_a32_kernel<<<dim3(8, 128), 256, 0, stream>>>(D0, dW3, db3, D1, 8192, 512, 512);
  // kernel spectra (reads D1, writes ASPEC)
  kfft_kernel<<<256, 512, 0, stream>>>(D1, TW, ASPEC);
  // FFT convolution: VT -> CT bf16 (CT overlays dead D0/D1)
  conv_kernel<<<dim3(256, 8), 512, 0, stream>>>(VT, ASPEC, TW, CT);
  // gated projection: (CT@Wo1 + bo1) * U -> G bf16 (overlays dead VT)
  gemm_gate_kernel<<<dim3(16, 512), 256, 0, stream>>>(CT, Wo1, bo1, U, G, 32768, 1024, 512);
  // final projection + residual
  gemm_final_kernel<<<dim3(8, 512), 256, 0, stream>>>(G, Wo2, bo2, x, out, 32768, 512, 1024);
}

// Round 3
// 914.745 us; speedup vs baseline: 2.3228x; 2.3228x over previous
//
#include <hip/hip_runtime.h>

// ---------------------------------------------------------------------------
// TNO-v2 forward. Round 3: all GEMMs on bf16 MFMA (16x16x32), fp32 in-LDS FFT
// conv. Workspace (192 MB, liveness-packed, MB offsets):
//   WT bf16 weights      0-6    (whole call)
//   XNb bf16             6-38   -> D0b 6-14, D1 14-30 -> CT 6-38 -> G 6-70
//   VTb bf16             38-70  (dies after conv)
//   ASPEC                70-87, TW 87-88 (die after conv)
//   CR bf16              88-120
//   U bf16               128-192
// ---------------------------------------------------------------------------

#define FFTN 8192
#define SWZ(p) ((p) ^ (((p) >> 8) & 31))

typedef unsigned short u16;
typedef unsigned int u32;
typedef __attribute__((ext_vector_type(8))) short bf16x8;
typedef __attribute__((ext_vector_type(4))) float f32x4;

__device__ __forceinline__ int brev13(int x) { return (int)(__brev((unsigned)x) >> 19); }
__device__ __forceinline__ float b2f(u16 u) {
  union { float f; u32 i; } c; c.i = ((u32)u) << 16; return c.f;
}
__device__ __forceinline__ u16 f2b(float f) {
  union { float f; u32 i; } c; c.f = f;
  u32 r = c.i + 0x7FFFu + ((c.i >> 16) & 1u);
  return (u16)(r >> 16);
}
__device__ __forceinline__ float silu_f(float x) { return x / (1.f + __expf(-x)); }

// ---------------- twiddles ---------------------------------------------------
__global__ void twiddle_init_kernel(float2* __restrict__ tw) {
  int k = blockIdx.x * blockDim.x + threadIdx.x;
  if (k < 4096) {
    double ang = -6.283185307179586476925286766559 * ((double)k / 8192.0);
    tw[k] = make_float2((float)cos(ang), (float)sin(ang));
  }
}

// ---------------- SimpleRMSNorm (fp32 in -> bf16 out, optional relu) --------
__global__ __launch_bounds__(256) void srms_bf16_kernel(
    const float* __restrict__ in, u16* __restrict__ out, int rows, int do_relu)
{
  int wave = threadIdx.x >> 6, lane = threadIdx.x & 63;
  int row = (blockIdx.x << 2) + wave;
  if (row >= rows) return;
  const float4* p = (const float4*)(in + (size_t)row * 512);
  float4 a = p[lane], b = p[lane + 64];
  float ss = a.x*a.x + a.y*a.y + a.z*a.z + a.w*a.w
           + b.x*b.x + b.y*b.y + b.z*b.z + b.w*b.w;
#pragma unroll
  for (int off = 32; off > 0; off >>= 1) ss += __shfl_xor(ss, off);
  float inv = 1.0f / (sqrtf(ss) * 0.04419417382415922f + 1e-8f);
  a.x *= inv; a.y *= inv; a.z *= inv; a.w *= inv;
  b.x *= inv; b.y *= inv; b.z *= inv; b.w *= inv;
  if (do_relu) {
    a.x = fmaxf(a.x, 0.f); a.y = fmaxf(a.y, 0.f); a.z = fmaxf(a.z, 0.f); a.w = fmaxf(a.w, 0.f);
    b.x = fmaxf(b.x, 0.f); b.y = fmaxf(b.y, 0.f); b.z = fmaxf(b.z, 0.f); b.w = fmaxf(b.w, 0.f);
  }
  u16* o = out + (size_t)row * 512;
  ushort4 s0, s1;
  s0.x = f2b(a.x); s0.y = f2b(a.y); s0.z = f2b(a.z); s0.w = f2b(a.w);
  s1.x = f2b(b.x); s1.y = f2b(b.y); s1.z = f2b(b.z); s1.w = f2b(b.w);
  *(ushort4*)(o + lane * 4) = s0;
  *(ushort4*)(o + 256 + lane * 4) = s1;
}

// ---------------- DPB layer 0 (bf16 out) ------------------------------------
__global__ __launch_bounds__(256) void dpb0_kernel(
    const float* __restrict__ Wp, const float* __restrict__ bp, u16* __restrict__ out)
{
  int wave = threadIdx.x >> 6, lane = threadIdx.x & 63;
  int row = (blockIdx.x << 2) + wave;   // circulant index 0..8191
  if (row >= 8192) return;
  float pv;
  if (row == 0 || row == 4096) pv = 0.f;
  else if (row < 4096) pv = (float)row;
  else pv = (float)(row - 8192);
  const float4* wp  = (const float4*)Wp;
  const float4* bpp = (const float4*)bp;
  float4 a = wp[lane], b = wp[lane + 64];
  float4 c = bpp[lane], d = bpp[lane + 64];
  a.x = fmaf(pv, a.x, c.x); a.y = fmaf(pv, a.y, c.y);
  a.z = fmaf(pv, a.z, c.z); a.w = fmaf(pv, a.w, c.w);
  b.x = fmaf(pv, b.x, d.x); b.y = fmaf(pv, b.y, d.y);
  b.z = fmaf(pv, b.z, d.z); b.w = fmaf(pv, b.w, d.w);
  float ss = a.x*a.x + a.y*a.y + a.z*a.z + a.w*a.w
           + b.x*b.x + b.y*b.y + b.z*b.z + b.w*b.w;
#pragma unroll
  for (int off = 32; off > 0; off >>= 1) ss += __shfl_xor(ss, off);
  float inv = 1.0f / (sqrtf(ss) * 0.04419417382415922f + 1e-8f);
  u16* o = out + (size_t)row * 512;
  ushort4 s0, s1;
  s0.x = f2b(fmaxf(a.x * inv, 0.f)); s0.y = f2b(fmaxf(a.y * inv, 0.f));
  s0.z = f2b(fmaxf(a.z * inv, 0.f)); s0.w = f2b(fmaxf(a.w * inv, 0.f));
  s1.x = f2b(fmaxf(b.x * inv, 0.f)); s1.y = f2b(fmaxf(b.y * inv, 0.f));
  s1.z = f2b(fmaxf(b.z * inv, 0.f)); s1.w = f2b(fmaxf(b.w * inv, 0.f));
  *(ushort4*)(o + lane * 4) = s0;
  *(ushort4*)(o + 256 + lane * 4) = s1;
}

// ---------------- weight transpose+cast: fp32 (R,C) -> bf16 (C,R) -----------
__global__ __launch_bounds__(256) void wtrans_kernel(
    const float* __restrict__ in, u16* __restrict__ out, int R, int C)
{
  __shared__ float tile[32][33];
  const int c0 = blockIdx.x << 5, r0 = blockIdx.y << 5;
  const int tx = threadIdx.x, ty = threadIdx.y;
#pragma unroll
  for (int i = 0; i < 32; i += 8)
    tile[ty + i][tx] = in[(size_t)(r0 + ty + i) * C + c0 + tx];
  __syncthreads();
#pragma unroll
  for (int i = 0; i < 32; i += 8)
    out[(size_t)(c0 + ty + i) * R + r0 + tx] = f2b(tile[tx][ty + i]);
}

// ---------------- bf16 transpose: (8, 512, 4096) -> (8, 4096, 512) ----------
__global__ __launch_bounds__(256) void transpose_b16_kernel(
    const u16* __restrict__ in, u16* __restrict__ out)
{
  __shared__ u16 tile[32][33];
  const int b = blockIdx.z;
  const int j0 = blockIdx.x << 5, c0 = blockIdx.y << 5;
  const int tx = threadIdx.x, ty = threadIdx.y;
  const u16* ip = in + ((size_t)b << 21);
  u16* op = out + ((size_t)b << 21);
#pragma unroll
  for (int i = 0; i < 32; i += 8)
    tile[ty + i][tx] = ip[(size_t)(c0 + ty + i) * 4096 + j0 + tx];
  __syncthreads();
#pragma unroll
  for (int i = 0; i < 32; i += 8)
    op[(size_t)(j0 + ty + i) * 512 + c0 + tx] = tile[tx][ty + i];
}

// ---------------- MFMA bf16 GEMM: C = A(MxK) @ Bt(NxK)^T + bias + epilogue --
// EPI: 0 plain fp32 | 1 silu bf16 | 2 silu bf16 transposed (VT: b,c,j)
//      3 (acc+bias)*aux16 bf16 | 4 acc+bias+auxf fp32
template <int EPI>
__global__ __launch_bounds__(256) void gemm_bf16_kernel(
    const u16* __restrict__ A, const u16* __restrict__ Bt,
    const float* __restrict__ bias, const u16* __restrict__ aux16,
    const float* __restrict__ auxf, void* __restrict__ Cv,
    int M, int N, int K)
{
  __shared__ __align__(16) u16 As[4096];   // [khalf(4)][m(128)][8 bf16]
  __shared__ __align__(16) u16 Bs[4096];   // [khalf(4)][n(128)][8 bf16]
  const int tid = threadIdx.x;
  const int lane = tid & 63;
  const int w = tid >> 6;
  const int wm = (w >> 1) << 6;
  const int wn = (w & 1) << 6;
  const int lm = lane & 15;
  const int lq = lane >> 4;
  const int bm = blockIdx.y << 7;
  const int bn = blockIdx.x << 7;

  const int sm = tid & 127;     // staging row within tile
  const int sk = tid >> 7;      // 0/1 -> khalf sk (phase 0) and 2+sk (phase 1)
  const u16* Ap = A + (size_t)(bm + sm) * K + sk * 8;
  const u16* Bp = Bt + (size_t)(bn + sm) * K + sk * 8;
  u16* As0 = As + ((sk)     * 128 + sm) * 8;
  u16* As1 = As + ((2 + sk) * 128 + sm) * 8;
  u16* Bs0 = Bs + ((sk)     * 128 + sm) * 8;
  u16* Bs1 = Bs + ((2 + sk) * 128 + sm) * 8;

  f32x4 acc[4][4];
#pragma unroll
  for (int i = 0; i < 4; i++)
#pragma unroll
    for (int j = 0; j < 4; j++) acc[i][j] = (f32x4){0.f, 0.f, 0.f, 0.f};

  for (int k0 = 0; k0 < K; k0 += 32) {
    const uint4 a0 = *(const uint4*)Ap;
    const uint4 a1 = *(const uint4*)(Ap + 16);
    const uint4 b0 = *(const uint4*)Bp;
    const uint4 b1 = *(const uint4*)(Bp + 16);
    Ap += 32; Bp += 32;
    __syncthreads();
    *(uint4*)As0 = a0; *(uint4*)As1 = a1;
    *(uint4*)Bs0 = b0; *(uint4*)Bs1 = b1;
    __syncthreads();
    bf16x8 af[4], bfr[4];
#pragma unroll
    for (int i = 0; i < 4; i++) {
      af[i]  = *(const bf16x8*)(As + (lq * 128 + wm + i * 16 + lm) * 8);
      bfr[i] = *(const bf16x8*)(Bs + (lq * 128 + wn + i * 16 + lm) * 8);
    }
#pragma unroll
    for (int i = 0; i < 4; i++)
#pragma unroll
      for (int j = 0; j < 4; j++)
        acc[i][j] = __builtin_amdgcn_mfma_f32_16x16x32_bf16(af[i], bfr[j], acc[i][j], 0, 0, 0);
  }

  // epilogue: lane holds C[m0 + r][n] for r=0..3 per (i,j) tile
#pragma unroll
  for (int i = 0; i < 4; i++) {
    const int m0 = bm + wm + i * 16 + lq * 4;
#pragma unroll
    for (int j = 0; j < 4; j++) {
      const int n = bn + wn + j * 16 + lm;
      const float bb = bias[n];
      const f32x4 v = acc[i][j];
      if constexpr (EPI == 2) {
        // store VT[(b*512 + c)*4096 + jseq], rows r are consecutive jseq
        const int b = m0 >> 12;
        const int jq = m0 & 4095;
        ushort4 s;
        s.x = f2b(silu_f(v[0] + bb)); s.y = f2b(silu_f(v[1] + bb));
        s.z = f2b(silu_f(v[2] + bb)); s.w = f2b(silu_f(v[3] + bb));
        *(ushort4*)((u16*)Cv + (((size_t)(b * 512 + n)) << 12) + jq) = s;
      } else {
#pragma unroll
        for (int r = 0; r < 4; r++) {
          const size_t idx = (size_t)(m0 + r) * N + n;
          const float val = v[r] + bb;
          if constexpr (EPI == 0) ((float*)Cv)[idx] = val;
          if constexpr (EPI == 1) ((u16*)Cv)[idx] = f2b(silu_f(val));
          if constexpr (EPI == 3) ((u16*)Cv)[idx] = f2b(val * b2f(aux16[idx]));
          if constexpr (EPI == 4) ((float*)Cv)[idx] = val + auxf[idx];
        }
      }
    }
  }
}

// ---------------- in-LDS 8192-pt FFT (512 threads) --------------------------
__device__ __forceinline__ void fft8192_dit(float* sr, float* si,
                                            const float2* __restrict__ tw)
{
  const int t = threadIdx.x;
  for (int s = 0; s < 13; s++) {
    __syncthreads();
    const int half = 1 << s;
#pragma unroll
    for (int bb = 0; bb < 8; bb++) {
      const int u = t + (bb << 9);
      const int j = u & (half - 1);
      const int i0 = ((u >> s) << (s + 1)) | j;
      const int i1 = i0 + half;
      const float2 w = tw[j << (12 - s)];
      const int p0 = SWZ(i0), p1 = SWZ(i1);
      const float br = sr[p1], bi = si[p1];
      const float tr = br * w.x - bi * w.y;
      const float ti = br * w.y + bi * w.x;
      const float ar = sr[p0], ai = si[p0];
      sr[p0] = ar + tr; si[p0] = ai + ti;
      sr[p1] = ar - tr; si[p1] = ai - ti;
    }
  }
  __syncthreads();
}

__device__ __forceinline__ void ifft8192_dif(float* sr, float* si,
                                             const float2* __restrict__ tw)
{
  const int t = threadIdx.x;
  for (int s = 12; s >= 0; s--) {
    __syncthreads();
    const int half = 1 << s;
#pragma unroll
    for (int bb = 0; bb < 8; bb++) {
      const int u = t + (bb << 9);
      const int j = u & (half - 1);
      const int i0 = ((u >> s) << (s + 1)) | j;
      const int i1 = i0 + half;
      const float2 w = tw[j << (12 - s)];  // conj applied below
      const int p0 = SWZ(i0), p1 = SWZ(i1);
      const float ar = sr[p0], ai = si[p0];
      const float br = sr[p1], bi = si[p1];
      const float dr = ar - br, di = ai - bi;
      sr[p0] = ar + br; si[p0] = ai + bi;
      sr[p1] = dr * w.x + di * w.y;
      si[p1] = di * w.x - dr * w.y;
    }
  }
  __syncthreads();
}

// ---------------- kernel spectra --------------------------------------------
__global__ __launch_bounds__(512) void kfft_kernel(
    const float* __restrict__ atab, const float2* __restrict__ tw,
    float2* __restrict__ aspec)
{
  __shared__ float sr[FFTN];
  __shared__ float si[FFTN];
  const int q = blockIdx.x;
  const int t = threadIdx.x;
#pragma unroll
  for (int it = 0; it < 16; it++) {
    const int r = t + (it << 9);
    const float2 v = *(const float2*)(atab + (size_t)r * 512 + 2 * q);
    const int d = SWZ(brev13(r));
    sr[d] = v.x; si[d] = v.y;
  }
  fft8192_dit(sr, si, tw);
  float2* O0 = aspec + (size_t)(2 * q) * 4097;
  float2* O1 = aspec + (size_t)(2 * q + 1) * 4097;
#pragma unroll 1
  for (int it = 0; it < 8; it++) {
    const int k = t + (it << 9);
    const int k2 = (FFTN - k) & (FFTN - 1);
    const float zr = sr[SWZ(k)],  zi = si[SWZ(k)];
    const float wr = sr[SWZ(k2)], wi = si[SWZ(k2)];
    O0[k] = make_float2(0.5f * (zr + wr), 0.5f * (zi - wi));
    O1[k] = make_float2(0.5f * (zi + wi), 0.5f * (wr - zr));
  }
  if (t == 0) {
    const float zr = sr[SWZ(4096)], zi = si[SWZ(4096)];
    O0[4096] = make_float2(zr, 0.f);
    O1[4096] = make_float2(zi, 0.f);
  }
}

// ---------------- pointwise spectral multiply -------------------------------
__device__ __forceinline__ void mulpoint(float* sr, float* si,
    const float2* __restrict__ A0, const float2* __restrict__ A1, int k)
{
  const int k2 = (FFTN - k) & (FFTN - 1);
  const int pk = SWZ(k), pk2 = SWZ(k2);
  const float zr = sr[pk],  zi = si[pk];
  const float wr = sr[pk2], wi = si[pk2];
  const float Xr = 0.5f * (zr + wr), Xi = 0.5f * (zi - wi);
  const float Yr = 0.5f * (zi + wi), Yi = 0.5f * (wr - zr);
  const float2 a0 = A0[k], a1 = A1[k];
  const float Pr = Xr * a0.x - Xi * a0.y, Pi = Xr * a0.y + Xi * a0.x;
  const float Qr = Yr * a1.x - Yi * a1.y, Qi = Yr * a1.y + Yi * a1.x;
  sr[pk]  = Pr - Qi;  si[pk]  = Pi + Qr;
  if (k2 != k) {      // k=0 / k=4096 self-conjugate: single write
    sr[pk2] = Pr + Qi;  si[pk2] = Qr - Pi;
  }
}

__global__ __launch_bounds__(512) void conv_kernel(
    const u16* __restrict__ vT,       // (8, 512, 4096) bf16
    const float2* __restrict__ aspec, // (512, 4097)
    const float2* __restrict__ tw,
    u16* __restrict__ outT)           // (8, 512, 4096) bf16
{
  __shared__ float sr[FFTN];
  __shared__ float si[FFTN];
  const int q = blockIdx.x;
  const int b = blockIdx.y;
  const int c0 = 2 * q, c1 = 2 * q + 1;
  const int t = threadIdx.x;
  const u16* p0 = vT + ((size_t)b * 512 + c0) * 4096;
  const u16* p1 = vT + ((size_t)b * 512 + c1) * 4096;
#pragma unroll
  for (int it = 0; it < 16; it++) {
    const int j = t + (it << 9);
    float a = 0.f, bb = 0.f;
    if (j < 4096) { a = b2f(p0[j]); bb = b2f(p1[j]); }
    const int d = SWZ(brev13(j));
    sr[d] = a; si[d] = bb;
  }
  fft8192_dit(sr, si, tw);
  const float2* A0 = aspec + (size_t)c0 * 4097;
  const float2* A1 = aspec + (size_t)c1 * 4097;
#pragma unroll 1
  for (int it = 0; it < 8; it++) {
    mulpoint(sr, si, A0, A1, t + (it << 9));
  }
  if (t == 0) mulpoint(sr, si, A0, A1, 4096);
  ifft8192_dif(sr, si, tw);
  const float scale = 1.0f / 8192.0f;
  u16* o0 = outT + ((size_t)b * 512 + c0) * 4096;
  u16* o1 = outT + ((size_t)b * 512 + c1) * 4096;
#pragma unroll
  for (int it = 0; it < 8; it++) {
    const int i = t + (it << 9);
    const int d = SWZ(brev13(i));
    o0[i] = f2b(sr[d] * scale);
    o1[i] = f2b(si[d] * scale);
  }
}

// ---------------------------------------------------------------------------
extern "C" void kernel_launch(void* const* d_in, const int* in_sizes, int n_in,
                              void* d_out, int out_size, void* d_ws, size_t ws_size,
                              hipStream_t stream)
{
  const float* x   = (const float*)d_in[0];
  const float* Wu  = (const float*)d_in[1];
  const float* bu  = (const float*)d_in[2];
  const float* Wv  = (const float*)d_in[3];
  const float* bv  = (const float*)d_in[4];
  const float* Wo1 = (const float*)d_in[5];
  const float* bo1 = (const float*)d_in[6];
  const float* Wo2 = (const float*)d_in[7];
  const float* bo2 = (const float*)d_in[8];
  const float* dWp = (const float*)d_in[9];
  const float* dbp = (const float*)d_in[10];
  const float* dW1 = (const float*)d_in[11];
  const float* db1 = (const float*)d_in[12];
  const float* dW2 = (const float*)d_in[13];
  const float* db2 = (const float*)d_in[14];
  const float* dW3 = (const float*)d_in[15];
  const float* db3 = (const float*)d_in[16];
  float* out = (float*)d_out;

  char* wsb = (char*)d_ws;
  const size_t MB = 1u << 20;
  // bf16 weight pool @ 0-6 MB
  u16* WuT  = (u16*)wsb;                    // 1024x512
  u16* WvT  = WuT + 524288;                 // 512x512
  u16* Wo1T = WvT + 262144;                 // 1024x512
  u16* Wo2T = Wo1T + 524288;                // 512x1024
  u16* dW1T = Wo2T + 524288;                // 512x512
  u16* dW2T = dW1T + 262144;
  u16* dW3T = dW2T + 262144;
  // activations / scratch
  u16*    XNb   = (u16*)(wsb + 6 * MB);     // 32768x512 bf16 (dies after u/v)
  u16*    D0b   = (u16*)(wsb + 6 * MB);     // 8192x512 bf16 (over dead XNb)
  float*  D1    = (float*)(wsb + 14 * MB);  // 8192x512 fp32
  u16*    CT    = (u16*)(wsb + 6 * MB);     // (8,512,4096) bf16 (after kfft)
  u16*    G     = (u16*)(wsb + 6 * MB);     // 32768x1024 bf16 (after transpose)
  u16*    VTb   = (u16*)(wsb + 38 * MB);    // (8,512,4096) bf16 (dies after conv)
  float2* ASPEC = (float2*)(wsb + 70 * MB); // 512x4097 c64 (~16.8MB)
  float2* TW    = (float2*)(wsb + 87 * MB); // 4096 c64
  u16*    CR    = (u16*)(wsb + 88 * MB);    // 32768x512 bf16
  u16*    U     = (u16*)(wsb + 128 * MB);   // 32768x1024 bf16

  dim3 wt_blk(32, 8);
  // weight transposes + casts
  wtrans_kernel<<<dim3(32, 16), wt_blk, 0, stream>>>(Wu, WuT, 512, 1024);
  wtrans_kernel<<<dim3(16, 16), wt_blk, 0, stream>>>(Wv, WvT, 512, 512);
  wtrans_kernel<<<dim3(32, 16), wt_blk, 0, stream>>>(Wo1, Wo1T, 512, 1024);
  wtrans_kernel<<<dim3(16, 32), wt_blk, 0, stream>>>(Wo2, Wo2T, 1024, 512);
  wtrans_kernel<<<dim3(16, 16), wt_blk, 0, stream>>>(dW1, dW1T, 512, 512);
  wtrans_kernel<<<dim3(16, 16), wt_blk, 0, stream>>>(dW2, dW2T, 512, 512);
  wtrans_kernel<<<dim3(16, 16), wt_blk, 0, stream>>>(dW3, dW3T, 512, 512);
  twiddle_init_kernel<<<8, 512, 0, stream>>>(TW);

  // pre-norm -> bf16
  srms_bf16_kernel<<<8192, 256, 0, stream>>>(x, XNb, 32768, 0);
  // v = silu(xn@Wv+bv) -> VTb channel-major bf16 (fused transpose)
  gemm_bf16_kernel<2><<<dim3(4, 256), 256, 0, stream>>>(XNb, WvT, bv, nullptr, nullptr, VTb, 32768, 512, 512);
  // u = silu(xn@Wu+bu) -> U bf16
  gemm_bf16_kernel<1><<<dim3(8, 256), 256, 0, stream>>>(XNb, WuT, bu, nullptr, nullptr, U, 32768, 1024, 512);

  // DPB MLP -> circulant table D1 (8192,512) fp32
  dpb0_kernel<<<2048, 256, 0, stream>>>(dWp, dbp, D0b);
  gemm_bf16_kernel<0><<<dim3(4, 64), 256, 0, stream>>>(D0b, dW1T, db1, nullptr, nullptr, D1, 8192, 512, 512);
  srms_bf16_kernel<<<2048, 256, 0, stream>>>(D1, D0b, 8192, 1);
  gemm_bf16_kernel<0><<<dim3(4, 64), 256, 0, stream>>>(D0b, dW2T, db2, nullptr, nullptr, D1, 8192, 512, 512);
  srms_bf16_kernel<<<2048, 256, 0, stream>>>(D1, D0b, 8192, 1);
  gemm_bf16_kernel<0><<<dim3(4, 64), 256, 0, stream>>>(D0b, dW3T, db3, nullptr, nullptr, D1, 8192, 512, 512);
  // kernel spectra
  kfft_kernel<<<256, 512, 0, stream>>>(D1, TW, ASPEC);
  // FFT conv: VTb -> CT (bf16, channel-major)
  conv_kernel<<<dim3(256, 8), 512, 0, stream>>>(VTb, ASPEC, TW, CT);
  // CT -> CR row-major bf16
  transpose_b16_kernel<<<dim3(128, 16, 8), wt_blk, 0, stream>>>(CT, CR);
  // gate: (CR@Wo1+bo1)*U -> G bf16
  gemm_bf16_kernel<3><<<dim3(8, 256), 256, 0, stream>>>(CR, Wo1T, bo1, U, nullptr, G, 32768, 1024, 512);
  // final: G@Wo2 + bo2 + x -> out fp32
  gemm_bf16_kernel<4><<<dim3(4, 256), 256, 0, stream>>>(G, Wo2T, bo2, nullptr, x, out, 32768, 512, 1024);
}

// Round 4
// 786.767 us; speedup vs baseline: 2.7006x; 1.1627x over previous
//
#include <hip/hip_runtime.h>

// ---------------------------------------------------------------------------
// TNO-v2 forward. Round 4: radix-4 in-LDS FFT (7 round-trips/direction vs 13)
// + global_load_lds 16B staging in the bf16 MFMA GEMM.
// Workspace (192 MB, liveness-packed, MB offsets):
//   WT bf16 weights      0-6    (whole call)
//   XNb bf16             6-38   -> D0b 6-14, D1 14-30 -> CT 6-38 -> G 6-70
//   VTb bf16             38-70  (dies after conv)
//   ASPEC                70-87, TW 87-88 (die after conv)
//   CR bf16              88-120
//   U bf16               128-192
// ---------------------------------------------------------------------------

#define FFTN 8192
#define SWZ(p) ((p) ^ (((p) >> 8) & 31))

typedef unsigned short u16;
typedef unsigned int u32;
typedef __attribute__((ext_vector_type(8))) short bf16x8;
typedef __attribute__((ext_vector_type(4))) float f32x4;

__device__ __forceinline__ int brev13(int x) { return (int)(__brev((unsigned)x) >> 19); }
__device__ __forceinline__ float b2f(u16 u) {
  union { float f; u32 i; } c; c.i = ((u32)u) << 16; return c.f;
}
__device__ __forceinline__ u16 f2b(float f) {
  union { float f; u32 i; } c; c.f = f;
  u32 r = c.i + 0x7FFFu + ((c.i >> 16) & 1u);
  return (u16)(r >> 16);
}
__device__ __forceinline__ float silu_f(float x) { return x / (1.f + __expf(-x)); }

// async global->LDS, 16B per lane; LDS dest must be wave-uniform base + lane*16
__device__ __forceinline__ void gload16(const void* g, void* l) {
  __builtin_amdgcn_global_load_lds(
      (const __attribute__((address_space(1))) u32*)g,
      (__attribute__((address_space(3))) u32*)l, 16, 0, 0);
}

// ---------------- twiddles ---------------------------------------------------
__global__ void twiddle_init_kernel(float2* __restrict__ tw) {
  int k = blockIdx.x * blockDim.x + threadIdx.x;
  if (k < 4096) {
    double ang = -6.283185307179586476925286766559 * ((double)k / 8192.0);
    tw[k] = make_float2((float)cos(ang), (float)sin(ang));
  }
}

// ---------------- SimpleRMSNorm (fp32 in -> bf16 out, optional relu) --------
__global__ __launch_bounds__(256) void srms_bf16_kernel(
    const float* __restrict__ in, u16* __restrict__ out, int rows, int do_relu)
{
  int wave = threadIdx.x >> 6, lane = threadIdx.x & 63;
  int row = (blockIdx.x << 2) + wave;
  if (row >= rows) return;
  const float4* p = (const float4*)(in + (size_t)row * 512);
  float4 a = p[lane], b = p[lane + 64];
  float ss = a.x*a.x + a.y*a.y + a.z*a.z + a.w*a.w
           + b.x*b.x + b.y*b.y + b.z*b.z + b.w*b.w;
#pragma unroll
  for (int off = 32; off > 0; off >>= 1) ss += __shfl_xor(ss, off);
  float inv = 1.0f / (sqrtf(ss) * 0.04419417382415922f + 1e-8f);
  a.x *= inv; a.y *= inv; a.z *= inv; a.w *= inv;
  b.x *= inv; b.y *= inv; b.z *= inv; b.w *= inv;
  if (do_relu) {
    a.x = fmaxf(a.x, 0.f); a.y = fmaxf(a.y, 0.f); a.z = fmaxf(a.z, 0.f); a.w = fmaxf(a.w, 0.f);
    b.x = fmaxf(b.x, 0.f); b.y = fmaxf(b.y, 0.f); b.z = fmaxf(b.z, 0.f); b.w = fmaxf(b.w, 0.f);
  }
  u16* o = out + (size_t)row * 512;
  ushort4 s0, s1;
  s0.x = f2b(a.x); s0.y = f2b(a.y); s0.z = f2b(a.z); s0.w = f2b(a.w);
  s1.x = f2b(b.x); s1.y = f2b(b.y); s1.z = f2b(b.z); s1.w = f2b(b.w);
  *(ushort4*)(o + lane * 4) = s0;
  *(ushort4*)(o + 256 + lane * 4) = s1;
}

// ---------------- DPB layer 0 (bf16 out) ------------------------------------
__global__ __launch_bounds__(256) void dpb0_kernel(
    const float* __restrict__ Wp, const float* __restrict__ bp, u16* __restrict__ out)
{
  int wave = threadIdx.x >> 6, lane = threadIdx.x & 63;
  int row = (blockIdx.x << 2) + wave;   // circulant index 0..8191
  if (row >= 8192) return;
  float pv;
  if (row == 0 || row == 4096) pv = 0.f;
  else if (row < 4096) pv = (float)row;
  else pv = (float)(row - 8192);
  const float4* wp  = (const float4*)Wp;
  const float4* bpp = (const float4*)bp;
  float4 a = wp[lane], b = wp[lane + 64];
  float4 c = bpp[lane], d = bpp[lane + 64];
  a.x = fmaf(pv, a.x, c.x); a.y = fmaf(pv, a.y, c.y);
  a.z = fmaf(pv, a.z, c.z); a.w = fmaf(pv, a.w, c.w);
  b.x = fmaf(pv, b.x, d.x); b.y = fmaf(pv, b.y, d.y);
  b.z = fmaf(pv, b.z, d.z); b.w = fmaf(pv, b.w, d.w);
  float ss = a.x*a.x + a.y*a.y + a.z*a.z + a.w*a.w
           + b.x*b.x + b.y*b.y + b.z*b.z + b.w*b.w;
#pragma unroll
  for (int off = 32; off > 0; off >>= 1) ss += __shfl_xor(ss, off);
  float inv = 1.0f / (sqrtf(ss) * 0.04419417382415922f + 1e-8f);
  u16* o = out + (size_t)row * 512;
  ushort4 s0, s1;
  s0.x = f2b(fmaxf(a.x * inv, 0.f)); s0.y = f2b(fmaxf(a.y * inv, 0.f));
  s0.z = f2b(fmaxf(a.z * inv, 0.f)); s0.w = f2b(fmaxf(a.w * inv, 0.f));
  s1.x = f2b(fmaxf(b.x * inv, 0.f)); s1.y = f2b(fmaxf(b.y * inv, 0.f));
  s1.z = f2b(fmaxf(b.z * inv, 0.f)); s1.w = f2b(fmaxf(b.w * inv, 0.f));
  *(ushort4*)(o + lane * 4) = s0;
  *(ushort4*)(o + 256 + lane * 4) = s1;
}

// ---------------- weight transpose+cast: fp32 (R,C) -> bf16 (C,R) -----------
__global__ __launch_bounds__(256) void wtrans_kernel(
    const float* __restrict__ in, u16* __restrict__ out, int R, int C)
{
  __shared__ float tile[32][33];
  const int c0 = blockIdx.x << 5, r0 = blockIdx.y << 5;
  const int tx = threadIdx.x, ty = threadIdx.y;
#pragma unroll
  for (int i = 0; i < 32; i += 8)
    tile[ty + i][tx] = in[(size_t)(r0 + ty + i) * C + c0 + tx];
  __syncthreads();
#pragma unroll
  for (int i = 0; i < 32; i += 8)
    out[(size_t)(c0 + ty + i) * R + r0 + tx] = f2b(tile[tx][ty + i]);
}

// ---------------- bf16 transpose: (8, 512, 4096) -> (8, 4096, 512) ----------
__global__ __launch_bounds__(256) void transpose_b16_kernel(
    const u16* __restrict__ in, u16* __restrict__ out)
{
  __shared__ u16 tile[32][33];
  const int b = blockIdx.z;
  const int j0 = blockIdx.x << 5, c0 = blockIdx.y << 5;
  const int tx = threadIdx.x, ty = threadIdx.y;
  const u16* ip = in + ((size_t)b << 21);
  u16* op = out + ((size_t)b << 21);
#pragma unroll
  for (int i = 0; i < 32; i += 8)
    tile[ty + i][tx] = ip[(size_t)(c0 + ty + i) * 4096 + j0 + tx];
  __syncthreads();
#pragma unroll
  for (int i = 0; i < 32; i += 8)
    op[(size_t)(j0 + ty + i) * 512 + c0 + tx] = tile[tx][ty + i];
}

// ---------------- MFMA bf16 GEMM: C = A(MxK) @ Bt(NxK)^T + bias + epilogue --
// EPI: 0 plain fp32 | 1 silu bf16 | 2 silu bf16 transposed (VT: b,c,j)
//      3 (acc+bias)*aux16 bf16 | 4 acc+bias+auxf fp32
template <int EPI>
__global__ __launch_bounds__(256) void gemm_bf16_kernel(
    const u16* __restrict__ A, const u16* __restrict__ Bt,
    const float* __restrict__ bias, const u16* __restrict__ aux16,
    const float* __restrict__ auxf, void* __restrict__ Cv,
    int M, int N, int K)
{
  __shared__ __align__(16) u16 As[4096];   // [khalf(4)][m(128)][8 bf16]
  __shared__ __align__(16) u16 Bs[4096];   // [khalf(4)][n(128)][8 bf16]
  const int tid = threadIdx.x;
  const int lane = tid & 63;
  const int w = tid >> 6;
  const int wm = (w >> 1) << 6;
  const int wn = (w & 1) << 6;
  const int lm = lane & 15;
  const int lq = lane >> 4;
  const int bm = blockIdx.y << 7;
  const int bn = blockIdx.x << 7;

  const int sm = tid & 127;     // staging row within tile
  const int sk = tid >> 7;      // 0/1 -> khalf sk (phase 0) and 2+sk (phase 1)
  const u16* Ap = A + (size_t)(bm + sm) * K + sk * 8;
  const u16* Bp = Bt + (size_t)(bn + sm) * K + sk * 8;
  u16* As0 = As + ((sk)     * 128 + sm) * 8;
  u16* As1 = As + ((2 + sk) * 128 + sm) * 8;
  u16* Bs0 = Bs + ((sk)     * 128 + sm) * 8;
  u16* Bs1 = Bs + ((2 + sk) * 128 + sm) * 8;

  f32x4 acc[4][4];
#pragma unroll
  for (int i = 0; i < 4; i++)
#pragma unroll
    for (int j = 0; j < 4; j++) acc[i][j] = (f32x4){0.f, 0.f, 0.f, 0.f};

  for (int k0 = 0; k0 < K; k0 += 32) {
    __syncthreads();                       // prior tile fully consumed
    gload16(Ap, As0); gload16(Ap + 16, As1);
    gload16(Bp, Bs0); gload16(Bp + 16, Bs1);
    Ap += 32; Bp += 32;
    __builtin_amdgcn_s_waitcnt(0);         // drain global_load_lds
    __syncthreads();
    bf16x8 af[4], bfr[4];
#pragma unroll
    for (int i = 0; i < 4; i++) {
      af[i]  = *(const bf16x8*)(As + (lq * 128 + wm + i * 16 + lm) * 8);
      bfr[i] = *(const bf16x8*)(Bs + (lq * 128 + wn + i * 16 + lm) * 8);
    }
#pragma unroll
    for (int i = 0; i < 4; i++)
#pragma unroll
      for (int j = 0; j < 4; j++)
        acc[i][j] = __builtin_amdgcn_mfma_f32_16x16x32_bf16(af[i], bfr[j], acc[i][j], 0, 0, 0);
  }

  // epilogue: lane holds C[m0 + r][n] for r=0..3 per (i,j) tile
#pragma unroll
  for (int i = 0; i < 4; i++) {
    const int m0 = bm + wm + i * 16 + lq * 4;
#pragma unroll
    for (int j = 0; j < 4; j++) {
      const int n = bn + wn + j * 16 + lm;
      const float bb = bias[n];
      const f32x4 v = acc[i][j];
      if constexpr (EPI == 2) {
        const int b = m0 >> 12;
        const int jq = m0 & 4095;
        ushort4 s;
        s.x = f2b(silu_f(v[0] + bb)); s.y = f2b(silu_f(v[1] + bb));
        s.z = f2b(silu_f(v[2] + bb)); s.w = f2b(silu_f(v[3] + bb));
        *(ushort4*)((u16*)Cv + (((size_t)(b * 512 + n)) << 12) + jq) = s;
      } else {
#pragma unroll
        for (int r = 0; r < 4; r++) {
          const size_t idx = (size_t)(m0 + r) * N + n;
          const float val = v[r] + bb;
          if constexpr (EPI == 0) ((float*)Cv)[idx] = val;
          if constexpr (EPI == 1) ((u16*)Cv)[idx] = f2b(silu_f(val));
          if constexpr (EPI == 3) ((u16*)Cv)[idx] = f2b(val * b2f(aux16[idx]));
          if constexpr (EPI == 4) ((float*)Cv)[idx] = val + auxf[idx];
        }
      }
    }
  }
}

// ---------------- radix-4 in-LDS 8192-pt FFT (512 threads) ------------------
// forward DIT: input at SWZ(brev13(j)), output natural (swizzled).
// Stage pairs s=(0,1),(2,3)..(10,11) fused as radix-4; stage 12 radix-2.
__device__ __forceinline__ void fft8192_dit(float* sr, float* si,
                                            const float2* __restrict__ tw)
{
  const int t = threadIdx.x;
  for (int s = 0; s < 12; s += 2) {
    __syncthreads();
    const int h = 1 << s;
#pragma unroll
    for (int bb = 0; bb < 4; bb++) {
      const int u = t + (bb << 9);          // [0,2048)
      const int j = u & (h - 1);
      const int base = ((u >> s) << (s + 2)) | j;
      const float2 w1 = tw[j << (12 - s)];
      const float2 w2 = tw[j << (11 - s)];
      const int q0 = SWZ(base), q1 = SWZ(base + h);
      const int q2 = SWZ(base + 2 * h), q3 = SWZ(base + 3 * h);
      const float ar = sr[q0], ai = si[q0];
      const float br = sr[q1], bi = si[q1];
      const float cr = sr[q2], ci = si[q2];
      const float dr = sr[q3], di = si[q3];
      // stage s: A=a+w1*b, B=a-w1*b, C=c+w1*d, D=c-w1*d
      const float t1r = br * w1.x - bi * w1.y, t1i = br * w1.y + bi * w1.x;
      const float t2r = dr * w1.x - di * w1.y, t2i = dr * w1.y + di * w1.x;
      const float Ar = ar + t1r, Ai = ai + t1i;
      const float Br = ar - t1r, Bi = ai - t1i;
      const float Cr = cr + t2r, Ci = ci + t2i;
      const float Dr = cr - t2r, Di = ci - t2i;
      // stage s+1: w2 on (A,C); (-i)*w2 on (B,D)
      const float t3r = Cr * w2.x - Ci * w2.y, t3i = Cr * w2.y + Ci * w2.x;
      const float pr  = Dr * w2.x - Di * w2.y, pi  = Dr * w2.y + Di * w2.x;
      const float t4r = pi, t4i = -pr;       // (-i)*(pr+i*pi)
      sr[q0] = Ar + t3r; si[q0] = Ai + t3i;
      sr[q2] = Ar - t3r; si[q2] = Ai - t3i;
      sr[q1] = Br + t4r; si[q1] = Bi + t4i;
      sr[q3] = Br - t4r; si[q3] = Bi - t4i;
    }
  }
  // final radix-2 stage s=12 (h=4096)
  __syncthreads();
#pragma unroll
  for (int bb = 0; bb < 8; bb++) {
    const int u = t + (bb << 9);             // [0,4096) == j == i0
    const float2 w = tw[u];
    const int p0 = SWZ(u), p1 = SWZ(u + 4096);
    const float br = sr[p1], bi = si[p1];
    const float trr = br * w.x - bi * w.y;
    const float tri = br * w.y + bi * w.x;
    const float ar = sr[p0], ai = si[p0];
    sr[p0] = ar + trr; si[p0] = ai + tri;
    sr[p1] = ar - trr; si[p1] = ai - tri;
  }
  __syncthreads();
}

// inverse DIF (conj twiddles): natural (swizzled) input, bit-reversed output.
// Stage pairs (12,11),(10,9)..(2,1) fused as radix-4; stage 0 radix-2.
__device__ __forceinline__ void ifft8192_dif(float* sr, float* si,
                                             const float2* __restrict__ tw)
{
  const int t = threadIdx.x;
  for (int s = 12; s >= 2; s -= 2) {
    __syncthreads();
    const int qq = 1 << (s - 1);
#pragma unroll
    for (int bb = 0; bb < 4; bb++) {
      const int u = t + (bb << 9);          // [0,2048)
      const int j = u & (qq - 1);
      const int base = ((u >> (s - 1)) << (s + 1)) | j;
      const float2 w2 = tw[j << (12 - s)];
      const float2 w1 = tw[j << (13 - s)];
      const int q0 = SWZ(base), q1 = SWZ(base + qq);
      const int q2 = SWZ(base + 2 * qq), q3 = SWZ(base + 3 * qq);
      const float ar = sr[q0], ai = si[q0];
      const float br = sr[q1], bi = si[q1];
      const float cr = sr[q2], ci = si[q2];
      const float dr = sr[q3], di = si[q3];
      // stage s: A=p0+p2, C=(p0-p2)*conj(w2), B=p1+p3, D=(p1-p3)*conj(w2)*i
      const float Ar = ar + cr, Ai = ai + ci;
      const float u1r = ar - cr, u1i = ai - ci;
      const float Cr = u1r * w2.x + u1i * w2.y, Ci = u1i * w2.x - u1r * w2.y;
      const float Br = br + dr, Bi = bi + di;
      const float u2r = br - dr, u2i = bi - di;
      const float d0r = u2r * w2.x + u2i * w2.y, d0i = u2i * w2.x - u2r * w2.y;
      const float Dr = -d0i, Di = d0r;       // *i
      // stage s-1: out0=A+B, out1=(A-B)*conj(w1), out2=C+D, out3=(C-D)*conj(w1)
      const float mr = Ar - Br, mi = Ai - Bi;
      const float nr = Cr - Dr, ni = Ci - Di;
      sr[q0] = Ar + Br;                  si[q0] = Ai + Bi;
      sr[q1] = mr * w1.x + mi * w1.y;    si[q1] = mi * w1.x - mr * w1.y;
      sr[q2] = Cr + Dr;                  si[q2] = Ci + Di;
      sr[q3] = nr * w1.x + ni * w1.y;    si[q3] = ni * w1.x - nr * w1.y;
    }
  }
  // final radix-2 stage s=0 (twiddle = 1)
  __syncthreads();
#pragma unroll
  for (int bb = 0; bb < 8; bb++) {
    const int u = t + (bb << 9);
    const int p0 = SWZ(2 * u), p1 = SWZ(2 * u + 1);
    const float ar = sr[p0], ai = si[p0];
    const float br = sr[p1], bi = si[p1];
    sr[p0] = ar + br; si[p0] = ai + bi;
    sr[p1] = ar - br; si[p1] = ai - bi;
  }
  __syncthreads();
}

// ---------------- kernel spectra --------------------------------------------
__global__ __launch_bounds__(512) void kfft_kernel(
    const float* __restrict__ atab, const float2* __restrict__ tw,
    float2* __restrict__ aspec)
{
  __shared__ float sr[FFTN];
  __shared__ float si[FFTN];
  const int q = blockIdx.x;
  const int t = threadIdx.x;
#pragma unroll
  for (int it = 0; it < 16; it++) {
    const int r = t + (it << 9);
    const float2 v = *(const float2*)(atab + (size_t)r * 512 + 2 * q);
    const int d = SWZ(brev13(r));
    sr[d] = v.x; si[d] = v.y;
  }
  fft8192_dit(sr, si, tw);
  float2* O0 = aspec + (size_t)(2 * q) * 4097;
  float2* O1 = aspec + (size_t)(2 * q + 1) * 4097;
#pragma unroll 1
  for (int it = 0; it < 8; it++) {
    const int k = t + (it << 9);
    const int k2 = (FFTN - k) & (FFTN - 1);
    const float zr = sr[SWZ(k)],  zi = si[SWZ(k)];
    const float wr = sr[SWZ(k2)], wi = si[SWZ(k2)];
    O0[k] = make_float2(0.5f * (zr + wr), 0.5f * (zi - wi));
    O1[k] = make_float2(0.5f * (zi + wi), 0.5f * (wr - zr));
  }
  if (t == 0) {
    const float zr = sr[SWZ(4096)], zi = si[SWZ(4096)];
    O0[4096] = make_float2(zr, 0.f);
    O1[4096] = make_float2(zi, 0.f);
  }
}

// ---------------- pointwise spectral multiply -------------------------------
__device__ __forceinline__ void mulpoint(float* sr, float* si,
    const float2* __restrict__ A0, const float2* __restrict__ A1, int k)
{
  const int k2 = (FFTN - k) & (FFTN - 1);
  const int pk = SWZ(k), pk2 = SWZ(k2);
  const float zr = sr[pk],  zi = si[pk];
  const float wr = sr[pk2], wi = si[pk2];
  const float Xr = 0.5f * (zr + wr), Xi = 0.5f * (zi - wi);
  const float Yr = 0.5f * (zi + wi), Yi = 0.5f * (wr - zr);
  const float2 a0 = A0[k], a1 = A1[k];
  const float Pr = Xr * a0.x - Xi * a0.y, Pi = Xr * a0.y + Xi * a0.x;
  const float Qr = Yr * a1.x - Yi * a1.y, Qi = Yr * a1.y + Yi * a1.x;
  sr[pk]  = Pr - Qi;  si[pk]  = Pi + Qr;
  if (k2 != k) {      // k=0 / k=4096 self-conjugate: single write
    sr[pk2] = Pr + Qi;  si[pk2] = Qr - Pi;
  }
}

__global__ __launch_bounds__(512) void conv_kernel(
    const u16* __restrict__ vT,       // (8, 512, 4096) bf16
    const float2* __restrict__ aspec, // (512, 4097)
    const float2* __restrict__ tw,
    u16* __restrict__ outT)           // (8, 512, 4096) bf16
{
  __shared__ float sr[FFTN];
  __shared__ float si[FFTN];
  const int q = blockIdx.x;
  const int b = blockIdx.y;
  const int c0 = 2 * q, c1 = 2 * q + 1;
  const int t = threadIdx.x;
  const u16* p0 = vT + ((size_t)b * 512 + c0) * 4096;
  const u16* p1 = vT + ((size_t)b * 512 + c1) * 4096;
#pragma unroll
  for (int it = 0; it < 16; it++) {
    const int j = t + (it << 9);
    float a = 0.f, bb = 0.f;
    if (j < 4096) { a = b2f(p0[j]); bb = b2f(p1[j]); }
    const int d = SWZ(brev13(j));
    sr[d] = a; si[d] = bb;
  }
  fft8192_dit(sr, si, tw);
  const float2* A0 = aspec + (size_t)c0 * 4097;
  const float2* A1 = aspec + (size_t)c1 * 4097;
#pragma unroll 1
  for (int it = 0; it < 8; it++) {
    mulpoint(sr, si, A0, A1, t + (it << 9));
  }
  if (t == 0) mulpoint(sr, si, A0, A1, 4096);
  ifft8192_dif(sr, si, tw);
  const float scale = 1.0f / 8192.0f;
  u16* o0 = outT + ((size_t)b * 512 + c0) * 4096;
  u16* o1 = outT + ((size_t)b * 512 + c1) * 4096;
#pragma unroll
  for (int it = 0; it < 8; it++) {
    const int i = t + (it << 9);
    const int d = SWZ(brev13(i));
    o0[i] = f2b(sr[d] * scale);
    o1[i] = f2b(si[d] * scale);
  }
}

// ---------------------------------------------------------------------------
extern "C" void kernel_launch(void* const* d_in, const int* in_sizes, int n_in,
                              void* d_out, int out_size, void* d_ws, size_t ws_size,
                              hipStream_t stream)
{
  const float* x   = (const float*)d_in[0];
  const float* Wu  = (const float*)d_in[1];
  const float* bu  = (const float*)d_in[2];
  const float* Wv  = (const float*)d_in[3];
  const float* bv  = (const float*)d_in[4];
  const float* Wo1 = (const float*)d_in[5];
  const float* bo1 = (const float*)d_in[6];
  const float* Wo2 = (const float*)d_in[7];
  const float* bo2 = (const float*)d_in[8];
  const float* dWp = (const float*)d_in[9];
  const float* dbp = (const float*)d_in[10];
  const float* dW1 = (const float*)d_in[11];
  const float* db1 = (const float*)d_in[12];
  const float* dW2 = (const float*)d_in[13];
  const float* db2 = (const float*)d_in[14];
  const float* dW3 = (const float*)d_in[15];
  const float* db3 = (const float*)d_in[16];
  float* out = (float*)d_out;

  char* wsb = (char*)d_ws;
  const size_t MB = 1u << 20;
  // bf16 weight pool @ 0-6 MB
  u16* WuT  = (u16*)wsb;                    // 1024x512
  u16* WvT  = WuT + 524288;                 // 512x512
  u16* Wo1T = WvT + 262144;                 // 1024x512
  u16* Wo2T = Wo1T + 524288;                // 512x1024
  u16* dW1T = Wo2T + 524288;                // 512x512
  u16* dW2T = dW1T + 262144;
  u16* dW3T = dW2T + 262144;
  // activations / scratch
  u16*    XNb   = (u16*)(wsb + 6 * MB);     // 32768x512 bf16 (dies after u/v)
  u16*    D0b   = (u16*)(wsb + 6 * MB);     // 8192x512 bf16 (over dead XNb)
  float*  D1    = (float*)(wsb + 14 * MB);  // 8192x512 fp32
  u16*    CT    = (u16*)(wsb + 6 * MB);     // (8,512,4096) bf16 (after kfft)
  u16*    G     = (u16*)(wsb + 6 * MB);     // 32768x1024 bf16 (after transpose)
  u16*    VTb   = (u16*)(wsb + 38 * MB);    // (8,512,4096) bf16 (dies after conv)
  float2* ASPEC = (float2*)(wsb + 70 * MB); // 512x4097 c64 (~16.8MB)
  float2* TW    = (float2*)(wsb + 87 * MB); // 4096 c64
  u16*    CR    = (u16*)(wsb + 88 * MB);    // 32768x512 bf16
  u16*    U     = (u16*)(wsb + 128 * MB);   // 32768x1024 bf16

  dim3 wt_blk(32, 8);
  // weight transposes + casts
  wtrans_kernel<<<dim3(32, 16), wt_blk, 0, stream>>>(Wu, WuT, 512, 1024);
  wtrans_kernel<<<dim3(16, 16), wt_blk, 0, stream>>>(Wv, WvT, 512, 512);
  wtrans_kernel<<<dim3(32, 16), wt_blk, 0, stream>>>(Wo1, Wo1T, 512, 1024);
  wtrans_kernel<<<dim3(16, 32), wt_blk, 0, stream>>>(Wo2, Wo2T, 1024, 512);
  wtrans_kernel<<<dim3(16, 16), wt_blk, 0, stream>>>(dW1, dW1T, 512, 512);
  wtrans_kernel<<<dim3(16, 16), wt_blk, 0, stream>>>(dW2, dW2T, 512, 512);
  wtrans_kernel<<<dim3(16, 16), wt_blk, 0, stream>>>(dW3, dW3T, 512, 512);
  twiddle_init_kernel<<<8, 512, 0, stream>>>(TW);

  // pre-norm -> bf16
  srms_bf16_kernel<<<8192, 256, 0, stream>>>(x, XNb, 32768, 0);
  // v = silu(xn@Wv+bv) -> VTb channel-major bf16 (fused transpose)
  gemm_bf16_kernel<2><<<dim3(4, 256), 256, 0, stream>>>(XNb, WvT, bv, nullptr, nullptr, VTb, 32768, 512, 512);
  // u = silu(xn@Wu+bu) -> U bf16
  gemm_bf16_kernel<1><<<dim3(8, 256), 256, 0, stream>>>(XNb, WuT, bu, nullptr, nullptr, U, 32768, 1024, 512);

  // DPB MLP -> circulant table D1 (8192,512) fp32
  dpb0_kernel<<<2048, 256, 0, stream>>>(dWp, dbp, D0b);
  gemm_bf16_kernel<0><<<dim3(4, 64), 256, 0, stream>>>(D0b, dW1T, db1, nullptr, nullptr, D1, 8192, 512, 512);
  srms_bf16_kernel<<<2048, 256, 0, stream>>>(D1, D0b, 8192, 1);
  gemm_bf16_kernel<0><<<dim3(4, 64), 256, 0, stream>>>(D0b, dW2T, db2, nullptr, nullptr, D1, 8192, 512, 512);
  srms_bf16_kernel<<<2048, 256, 0, stream>>>(D1, D0b, 8192, 1);
  gemm_bf16_kernel<0><<<dim3(4, 64), 256, 0, stream>>>(D0b, dW3T, db3, nullptr, nullptr, D1, 8192, 512, 512);
  // kernel spectra
  kfft_kernel<<<256, 512, 0, stream>>>(D1, TW, ASPEC);
  // FFT conv: VTb -> CT (bf16, channel-major)
  conv_kernel<<<dim3(256, 8), 512, 0, stream>>>(VTb, ASPEC, TW, CT);
  // CT -> CR row-major bf16
  transpose_b16_kernel<<<dim3(128, 16, 8), wt_blk, 0, stream>>>(CT, CR);
  // gate: (CR@Wo1+bo1)*U -> G bf16
  gemm_bf16_kernel<3><<<dim3(8, 256), 256, 0, stream>>>(CR, Wo1T, bo1, U, nullptr, G, 32768, 1024, 512);
  // final: G@Wo2 + bo2 + x -> out fp32
  gemm_bf16_kernel<4><<<dim3(4, 256), 256, 0, stream>>>(G, Wo2T, bo2, nullptr, x, out, 32768, 512, 1024);
}

// Round 5
// 745.913 us; speedup vs baseline: 2.8486x; 1.0548x over previous
//
#include <hip/hip_runtime.h>
#include <hip/hip_fp16.h>

// ---------------------------------------------------------------------------
// TNO-v2 forward. Round 5: conv FFT state packed as half2 (fp32 math, fp16
// LDS storage) -> half the LDS instrs + 32KB LDS -> 4 blocks/CU. Inverse
// scale folded into ASPEC. dW3 GEMM writes transposed fp32 so kfft reads
// coalesced. GEMMs unchanged from round 4.
// ---------------------------------------------------------------------------

#define FFTN 8192
#define SWZ(p) ((p) ^ (((p) >> 8) & 31))

typedef unsigned short u16;
typedef unsigned int u32;
typedef __attribute__((ext_vector_type(8))) short bf16x8;
typedef __attribute__((ext_vector_type(4))) float f32x4;

__device__ __forceinline__ int brev13(int x) { return (int)(__brev((unsigned)x) >> 19); }
__device__ __forceinline__ float b2f(u16 u) {
  union { float f; u32 i; } c; c.i = ((u32)u) << 16; return c.f;
}
__device__ __forceinline__ u16 f2b(float f) {
  union { float f; u32 i; } c; c.f = f;
  u32 r = c.i + 0x7FFFu + ((c.i >> 16) & 1u);
  return (u16)(r >> 16);
}
__device__ __forceinline__ float silu_f(float x) { return x / (1.f + __expf(-x)); }

// packed half2 <-> 2xfloat
__device__ __forceinline__ float2 up2(u32 v) {
  __half2 h = __builtin_bit_cast(__half2, v);
  return make_float2(__low2float(h), __high2float(h));
}
__device__ __forceinline__ u32 dn2(float r, float i) {
  __half2 h = __floats2half2_rn(r, i);
  return __builtin_bit_cast(u32, h);
}

// async global->LDS, 16B per lane; LDS dest must be wave-uniform base + lane*16
__device__ __forceinline__ void gload16(const void* g, void* l) {
  __builtin_amdgcn_global_load_lds(
      (const __attribute__((address_space(1))) u32*)g,
      (__attribute__((address_space(3))) u32*)l, 16, 0, 0);
}

// ---------------- twiddles ---------------------------------------------------
__global__ void twiddle_init_kernel(float2* __restrict__ tw) {
  int k = blockIdx.x * blockDim.x + threadIdx.x;
  if (k < 4096) {
    double ang = -6.283185307179586476925286766559 * ((double)k / 8192.0);
    tw[k] = make_float2((float)cos(ang), (float)sin(ang));
  }
}

// ---------------- SimpleRMSNorm (fp32 in -> bf16 out, optional relu) --------
__global__ __launch_bounds__(256) void srms_bf16_kernel(
    const float* __restrict__ in, u16* __restrict__ out, int rows, int do_relu)
{
  int wave = threadIdx.x >> 6, lane = threadIdx.x & 63;
  int row = (blockIdx.x << 2) + wave;
  if (row >= rows) return;
  const float4* p = (const float4*)(in + (size_t)row * 512);
  float4 a = p[lane], b = p[lane + 64];
  float ss = a.x*a.x + a.y*a.y + a.z*a.z + a.w*a.w
           + b.x*b.x + b.y*b.y + b.z*b.z + b.w*b.w;
#pragma unroll
  for (int off = 32; off > 0; off >>= 1) ss += __shfl_xor(ss, off);
  float inv = 1.0f / (sqrtf(ss) * 0.04419417382415922f + 1e-8f);
  a.x *= inv; a.y *= inv; a.z *= inv; a.w *= inv;
  b.x *= inv; b.y *= inv; b.z *= inv; b.w *= inv;
  if (do_relu) {
    a.x = fmaxf(a.x, 0.f); a.y = fmaxf(a.y, 0.f); a.z = fmaxf(a.z, 0.f); a.w = fmaxf(a.w, 0.f);
    b.x = fmaxf(b.x, 0.f); b.y = fmaxf(b.y, 0.f); b.z = fmaxf(b.z, 0.f); b.w = fmaxf(b.w, 0.f);
  }
  u16* o = out + (size_t)row * 512;
  ushort4 s0, s1;
  s0.x = f2b(a.x); s0.y = f2b(a.y); s0.z = f2b(a.z); s0.w = f2b(a.w);
  s1.x = f2b(b.x); s1.y = f2b(b.y); s1.z = f2b(b.z); s1.w = f2b(b.w);
  *(ushort4*)(o + lane * 4) = s0;
  *(ushort4*)(o + 256 + lane * 4) = s1;
}

// ---------------- DPB layer 0 (bf16 out) ------------------------------------
__global__ __launch_bounds__(256) void dpb0_kernel(
    const float* __restrict__ Wp, const float* __restrict__ bp, u16* __restrict__ out)
{
  int wave = threadIdx.x >> 6, lane = threadIdx.x & 63;
  int row = (blockIdx.x << 2) + wave;   // circulant index 0..8191
  if (row >= 8192) return;
  float pv;
  if (row == 0 || row == 4096) pv = 0.f;
  else if (row < 4096) pv = (float)row;
  else pv = (float)(row - 8192);
  const float4* wp  = (const float4*)Wp;
  const float4* bpp = (const float4*)bp;
  float4 a = wp[lane], b = wp[lane + 64];
  float4 c = bpp[lane], d = bpp[lane + 64];
  a.x = fmaf(pv, a.x, c.x); a.y = fmaf(pv, a.y, c.y);
  a.z = fmaf(pv, a.z, c.z); a.w = fmaf(pv, a.w, c.w);
  b.x = fmaf(pv, b.x, d.x); b.y = fmaf(pv, b.y, d.y);
  b.z = fmaf(pv, b.z, d.z); b.w = fmaf(pv, b.w, d.w);
  float ss = a.x*a.x + a.y*a.y + a.z*a.z + a.w*a.w
           + b.x*b.x + b.y*b.y + b.z*b.z + b.w*b.w;
#pragma unroll
  for (int off = 32; off > 0; off >>= 1) ss += __shfl_xor(ss, off);
  float inv = 1.0f / (sqrtf(ss) * 0.04419417382415922f + 1e-8f);
  u16* o = out + (size_t)row * 512;
  ushort4 s0, s1;
  s0.x = f2b(fmaxf(a.x * inv, 0.f)); s0.y = f2b(fmaxf(a.y * inv, 0.f));
  s0.z = f2b(fmaxf(a.z * inv, 0.f)); s0.w = f2b(fmaxf(a.w * inv, 0.f));
  s1.x = f2b(fmaxf(b.x * inv, 0.f)); s1.y = f2b(fmaxf(b.y * inv, 0.f));
  s1.z = f2b(fmaxf(b.z * inv, 0.f)); s1.w = f2b(fmaxf(b.w * inv, 0.f));
  *(ushort4*)(o + lane * 4) = s0;
  *(ushort4*)(o + 256 + lane * 4) = s1;
}

// ---------------- weight transpose+cast: fp32 (R,C) -> bf16 (C,R) -----------
__global__ __launch_bounds__(256) void wtrans_kernel(
    const float* __restrict__ in, u16* __restrict__ out, int R, int C)
{
  __shared__ float tile[32][33];
  const int c0 = blockIdx.x << 5, r0 = blockIdx.y << 5;
  const int tx = threadIdx.x, ty = threadIdx.y;
#pragma unroll
  for (int i = 0; i < 32; i += 8)
    tile[ty + i][tx] = in[(size_t)(r0 + ty + i) * C + c0 + tx];
  __syncthreads();
#pragma unroll
  for (int i = 0; i < 32; i += 8)
    out[(size_t)(c0 + ty + i) * R + r0 + tx] = f2b(tile[tx][ty + i]);
}

// ---------------- bf16 transpose: (8, 512, 4096) -> (8, 4096, 512) ----------
__global__ __launch_bounds__(256) void transpose_b16_kernel(
    const u16* __restrict__ in, u16* __restrict__ out)
{
  __shared__ u16 tile[32][33];
  const int b = blockIdx.z;
  const int j0 = blockIdx.x << 5, c0 = blockIdx.y << 5;
  const int tx = threadIdx.x, ty = threadIdx.y;
  const u16* ip = in + ((size_t)b << 21);
  u16* op = out + ((size_t)b << 21);
#pragma unroll
  for (int i = 0; i < 32; i += 8)
    tile[ty + i][tx] = ip[(size_t)(c0 + ty + i) * 4096 + j0 + tx];
  __syncthreads();
#pragma unroll
  for (int i = 0; i < 32; i += 8)
    op[(size_t)(j0 + ty + i) * 512 + c0 + tx] = tile[tx][ty + i];
}

// ---------------- MFMA bf16 GEMM: C = A(MxK) @ Bt(NxK)^T + bias + epilogue --
// EPI: 0 plain fp32 | 1 silu bf16 | 2 silu bf16 transposed (VT: b,c,j)
//      3 (acc+bias)*aux16 bf16 | 4 acc+bias+auxf fp32 | 5 fp32 transposed C^T
template <int EPI>
__global__ __launch_bounds__(256) void gemm_bf16_kernel(
    const u16* __restrict__ A, const u16* __restrict__ Bt,
    const float* __restrict__ bias, const u16* __restrict__ aux16,
    const float* __restrict__ auxf, void* __restrict__ Cv,
    int M, int N, int K)
{
  __shared__ __align__(16) u16 As[4096];   // [khalf(4)][m(128)][8 bf16]
  __shared__ __align__(16) u16 Bs[4096];   // [khalf(4)][n(128)][8 bf16]
  const int tid = threadIdx.x;
  const int lane = tid & 63;
  const int w = tid >> 6;
  const int wm = (w >> 1) << 6;
  const int wn = (w & 1) << 6;
  const int lm = lane & 15;
  const int lq = lane >> 4;
  const int bm = blockIdx.y << 7;
  const int bn = blockIdx.x << 7;

  const int sm = tid & 127;     // staging row within tile
  const int sk = tid >> 7;      // 0/1 -> khalf sk (phase 0) and 2+sk (phase 1)
  const u16* Ap = A + (size_t)(bm + sm) * K + sk * 8;
  const u16* Bp = Bt + (size_t)(bn + sm) * K + sk * 8;
  u16* As0 = As + ((sk)     * 128 + sm) * 8;
  u16* As1 = As + ((2 + sk) * 128 + sm) * 8;
  u16* Bs0 = Bs + ((sk)     * 128 + sm) * 8;
  u16* Bs1 = Bs + ((2 + sk) * 128 + sm) * 8;

  f32x4 acc[4][4];
#pragma unroll
  for (int i = 0; i < 4; i++)
#pragma unroll
    for (int j = 0; j < 4; j++) acc[i][j] = (f32x4){0.f, 0.f, 0.f, 0.f};

  for (int k0 = 0; k0 < K; k0 += 32) {
    __syncthreads();                       // prior tile fully consumed
    gload16(Ap, As0); gload16(Ap + 16, As1);
    gload16(Bp, Bs0); gload16(Bp + 16, Bs1);
    Ap += 32; Bp += 32;
    __builtin_amdgcn_s_waitcnt(0);         // drain global_load_lds
    __syncthreads();
    bf16x8 af[4], bfr[4];
#pragma unroll
    for (int i = 0; i < 4; i++) {
      af[i]  = *(const bf16x8*)(As + (lq * 128 + wm + i * 16 + lm) * 8);
      bfr[i] = *(const bf16x8*)(Bs + (lq * 128 + wn + i * 16 + lm) * 8);
    }
#pragma unroll
    for (int i = 0; i < 4; i++)
#pragma unroll
      for (int j = 0; j < 4; j++)
        acc[i][j] = __builtin_amdgcn_mfma_f32_16x16x32_bf16(af[i], bfr[j], acc[i][j], 0, 0, 0);
  }

  // epilogue: lane holds C[m0 + r][n] for r=0..3 per (i,j) tile
#pragma unroll
  for (int i = 0; i < 4; i++) {
    const int m0 = bm + wm + i * 16 + lq * 4;
#pragma unroll
    for (int j = 0; j < 4; j++) {
      const int n = bn + wn + j * 16 + lm;
      const float bb = bias[n];
      const f32x4 v = acc[i][j];
      if constexpr (EPI == 2) {
        const int b = m0 >> 12;
        const int jq = m0 & 4095;
        ushort4 s;
        s.x = f2b(silu_f(v[0] + bb)); s.y = f2b(silu_f(v[1] + bb));
        s.z = f2b(silu_f(v[2] + bb)); s.w = f2b(silu_f(v[3] + bb));
        *(ushort4*)((u16*)Cv + (((size_t)(b * 512 + n)) << 12) + jq) = s;
      } else if constexpr (EPI == 5) {
        // C^T[n][m] fp32, rows r consecutive in m
        float4 o = make_float4(v[0] + bb, v[1] + bb, v[2] + bb, v[3] + bb);
        *(float4*)((float*)Cv + (size_t)n * M + m0) = o;
      } else {
#pragma unroll
        for (int r = 0; r < 4; r++) {
          const size_t idx = (size_t)(m0 + r) * N + n;
          const float val = v[r] + bb;
          if constexpr (EPI == 0) ((float*)Cv)[idx] = val;
          if constexpr (EPI == 1) ((u16*)Cv)[idx] = f2b(silu_f(val));
          if constexpr (EPI == 3) ((u16*)Cv)[idx] = f2b(val * b2f(aux16[idx]));
          if constexpr (EPI == 4) ((float*)Cv)[idx] = val + auxf[idx];
        }
      }
    }
  }
}

// ============================================================================
// fp32 FFT core (kfft only)
// ============================================================================
__device__ __forceinline__ void fft8192_dit(float* sr, float* si,
                                            const float2* __restrict__ tw)
{
  const int t = threadIdx.x;
  for (int s = 0; s < 12; s += 2) {
    __syncthreads();
    const int h = 1 << s;
#pragma unroll
    for (int bb = 0; bb < 4; bb++) {
      const int u = t + (bb << 9);
      const int j = u & (h - 1);
      const int base = ((u >> s) << (s + 2)) | j;
      const float2 w1 = tw[j << (12 - s)];
      const float2 w2 = tw[j << (11 - s)];
      const int q0 = SWZ(base), q1 = SWZ(base + h);
      const int q2 = SWZ(base + 2 * h), q3 = SWZ(base + 3 * h);
      const float ar = sr[q0], ai = si[q0];
      const float br = sr[q1], bi = si[q1];
      const float cr = sr[q2], ci = si[q2];
      const float dr = sr[q3], di = si[q3];
      const float t1r = br * w1.x - bi * w1.y, t1i = br * w1.y + bi * w1.x;
      const float t2r = dr * w1.x - di * w1.y, t2i = dr * w1.y + di * w1.x;
      const float Ar = ar + t1r, Ai = ai + t1i;
      const float Br = ar - t1r, Bi = ai - t1i;
      const float Cr = cr + t2r, Ci = ci + t2i;
      const float Dr = cr - t2r, Di = ci - t2i;
      const float t3r = Cr * w2.x - Ci * w2.y, t3i = Cr * w2.y + Ci * w2.x;
      const float pr  = Dr * w2.x - Di * w2.y, pi  = Dr * w2.y + Di * w2.x;
      const float t4r = pi, t4i = -pr;
      sr[q0] = Ar + t3r; si[q0] = Ai + t3i;
      sr[q2] = Ar - t3r; si[q2] = Ai - t3i;
      sr[q1] = Br + t4r; si[q1] = Bi + t4i;
      sr[q3] = Br - t4r; si[q3] = Bi - t4i;
    }
  }
  __syncthreads();
#pragma unroll
  for (int bb = 0; bb < 8; bb++) {
    const int u = t + (bb << 9);
    const float2 w = tw[u];
    const int p0 = SWZ(u), p1 = SWZ(u + 4096);
    const float br = sr[p1], bi = si[p1];
    const float trr = br * w.x - bi * w.y;
    const float tri = br * w.y + bi * w.x;
    const float ar = sr[p0], ai = si[p0];
    sr[p0] = ar + trr; si[p0] = ai + tri;
    sr[p1] = ar - trr; si[p1] = ai - tri;
  }
  __syncthreads();
}

// ---------------- kernel spectra (fp32, reads transposed D1T coalesced) -----
__global__ __launch_bounds__(512) void kfft_kernel(
    const float* __restrict__ D1T,    // (512, 8192) fp32
    const float2* __restrict__ tw,
    float2* __restrict__ aspec)
{
  __shared__ float sr[FFTN];
  __shared__ float si[FFTN];
  const int q = blockIdx.x;
  const int t = threadIdx.x;
  const float* row0 = D1T + ((size_t)(2 * q)) * 8192;
  const float* row1 = row0 + 8192;
#pragma unroll
  for (int it = 0; it < 16; it++) {
    const int r = t + (it << 9);
    const int d = SWZ(brev13(r));
    sr[d] = row0[r]; si[d] = row1[r];
  }
  fft8192_dit(sr, si, tw);
  // fold inverse-FFT 1/8192 scale into the spectra
  const float sc = 1.0f / 8192.0f;
  float2* O0 = aspec + (size_t)(2 * q) * 4097;
  float2* O1 = aspec + (size_t)(2 * q + 1) * 4097;
#pragma unroll 1
  for (int it = 0; it < 8; it++) {
    const int k = t + (it << 9);
    const int k2 = (FFTN - k) & (FFTN - 1);
    const float zr = sr[SWZ(k)],  zi = si[SWZ(k)];
    const float wr = sr[SWZ(k2)], wi = si[SWZ(k2)];
    O0[k] = make_float2(0.5f * sc * (zr + wr), 0.5f * sc * (zi - wi));
    O1[k] = make_float2(0.5f * sc * (zi + wi), 0.5f * sc * (wr - zr));
  }
  if (t == 0) {
    const float zr = sr[SWZ(4096)], zi = si[SWZ(4096)];
    O0[4096] = make_float2(zr * sc, 0.f);
    O1[4096] = make_float2(zi * sc, 0.f);
  }
}

// ============================================================================
// half2-packed FFT core (conv): fp32 math, fp16 storage, one u32 word/point
// ============================================================================
__device__ __forceinline__ void fft8192_dit_h2(u32* S, const float2* __restrict__ tw)
{
  const int t = threadIdx.x;
  for (int s = 0; s < 12; s += 2) {
    __syncthreads();
    const int h = 1 << s;
#pragma unroll
    for (int bb = 0; bb < 4; bb++) {
      const int u = t + (bb << 9);
      const int j = u & (h - 1);
      const int base = ((u >> s) << (s + 2)) | j;
      const float2 w1 = tw[j << (12 - s)];
      const float2 w2 = tw[j << (11 - s)];
      const int q0 = SWZ(base), q1 = SWZ(base + h);
      const int q2 = SWZ(base + 2 * h), q3 = SWZ(base + 3 * h);
      const float2 a = up2(S[q0]), b = up2(S[q1]);
      const float2 c = up2(S[q2]), d = up2(S[q3]);
      const float t1r = b.x * w1.x - b.y * w1.y, t1i = b.x * w1.y + b.y * w1.x;
      const float t2r = d.x * w1.x - d.y * w1.y, t2i = d.x * w1.y + d.y * w1.x;
      const float Ar = a.x + t1r, Ai = a.y + t1i;
      const float Br = a.x - t1r, Bi = a.y - t1i;
      const float Cr = c.x + t2r, Ci = c.y + t2i;
      const float Dr = c.x - t2r, Di = c.y - t2i;
      const float t3r = Cr * w2.x - Ci * w2.y, t3i = Cr * w2.y + Ci * w2.x;
      const float pr  = Dr * w2.x - Di * w2.y, pi  = Dr * w2.y + Di * w2.x;
      const float t4r = pi, t4i = -pr;
      S[q0] = dn2(Ar + t3r, Ai + t3i);
      S[q2] = dn2(Ar - t3r, Ai - t3i);
      S[q1] = dn2(Br + t4r, Bi + t4i);
      S[q3] = dn2(Br - t4r, Bi - t4i);
    }
  }
  __syncthreads();
#pragma unroll
  for (int bb = 0; bb < 8; bb++) {
    const int u = t + (bb << 9);
    const float2 w = tw[u];
    const int p0 = SWZ(u), p1 = SWZ(u + 4096);
    const float2 b = up2(S[p1]);
    const float trr = b.x * w.x - b.y * w.y;
    const float tri = b.x * w.y + b.y * w.x;
    const float2 a = up2(S[p0]);
    S[p0] = dn2(a.x + trr, a.y + tri);
    S[p1] = dn2(a.x - trr, a.y - tri);
  }
  __syncthreads();
}

__device__ __forceinline__ void ifft8192_dif_h2(u32* S, const float2* __restrict__ tw)
{
  const int t = threadIdx.x;
  for (int s = 12; s >= 2; s -= 2) {
    __syncthreads();
    const int qq = 1 << (s - 1);
#pragma unroll
    for (int bb = 0; bb < 4; bb++) {
      const int u = t + (bb << 9);
      const int j = u & (qq - 1);
      const int base = ((u >> (s - 1)) << (s + 1)) | j;
      const float2 w2 = tw[j << (12 - s)];
      const float2 w1 = tw[j << (13 - s)];
      const int q0 = SWZ(base), q1 = SWZ(base + qq);
      const int q2 = SWZ(base + 2 * qq), q3 = SWZ(base + 3 * qq);
      const float2 a = up2(S[q0]), b = up2(S[q1]);
      const float2 c = up2(S[q2]), d = up2(S[q3]);
      const float Ar = a.x + c.x, Ai = a.y + c.y;
      const float u1r = a.x - c.x, u1i = a.y - c.y;
      const float Cr = u1r * w2.x + u1i * w2.y, Ci = u1i * w2.x - u1r * w2.y;
      const float Br = b.x + d.x, Bi = b.y + d.y;
      const float u2r = b.x - d.x, u2i = b.y - d.y;
      const float d0r = u2r * w2.x + u2i * w2.y, d0i = u2i * w2.x - u2r * w2.y;
      const float Dr = -d0i, Di = d0r;
      const float mr = Ar - Br, mi = Ai - Bi;
      const float nr = Cr - Dr, ni = Ci - Di;
      S[q0] = dn2(Ar + Br, Ai + Bi);
      S[q1] = dn2(mr * w1.x + mi * w1.y, mi * w1.x - mr * w1.y);
      S[q2] = dn2(Cr + Dr, Ci + Di);
      S[q3] = dn2(nr * w1.x + ni * w1.y, ni * w1.x - nr * w1.y);
    }
  }
  __syncthreads();
#pragma unroll
  for (int bb = 0; bb < 8; bb++) {
    const int u = t + (bb << 9);
    const int p0 = SWZ(2 * u), p1 = SWZ(2 * u + 1);
    const float2 a = up2(S[p0]);
    const float2 b = up2(S[p1]);
    S[p0] = dn2(a.x + b.x, a.y + b.y);
    S[p1] = dn2(a.x - b.x, a.y - b.y);
  }
  __syncthreads();
}

// pointwise spectral multiply (ASPEC pre-scaled by 1/8192)
__device__ __forceinline__ void mulpoint_h2(u32* S,
    const float2* __restrict__ A0, const float2* __restrict__ A1, int k)
{
  const int k2 = (FFTN - k) & (FFTN - 1);
  const int pk = SWZ(k), pk2 = SWZ(k2);
  const float2 z = up2(S[pk]);
  const float2 w = up2(S[pk2]);
  const float Xr = 0.5f * (z.x + w.x), Xi = 0.5f * (z.y - w.y);
  const float Yr = 0.5f * (z.y + w.y), Yi = 0.5f * (w.x - z.x);
  const float2 a0 = A0[k], a1 = A1[k];
  const float Pr = Xr * a0.x - Xi * a0.y, Pi = Xr * a0.y + Xi * a0.x;
  const float Qr = Yr * a1.x - Yi * a1.y, Qi = Yr * a1.y + Yi * a1.x;
  S[pk] = dn2(Pr - Qi, Pi + Qr);
  if (k2 != k) {      // k=0 / k=4096 self-conjugate: single write
    S[pk2] = dn2(Pr + Qi, Qr - Pi);
  }
}

__global__ __launch_bounds__(512, 8) void conv_kernel(
    const u16* __restrict__ vT,       // (8, 512, 4096) bf16
    const float2* __restrict__ aspec, // (512, 4097) pre-scaled
    const float2* __restrict__ tw,
    u16* __restrict__ outT)           // (8, 512, 4096) bf16
{
  __shared__ u32 S[FFTN];             // 32 KB: half2-packed complex
  const int q = blockIdx.x;
  const int b = blockIdx.y;
  const int c0 = 2 * q, c1 = 2 * q + 1;
  const int t = threadIdx.x;
  const u16* p0 = vT + ((size_t)b * 512 + c0) * 4096;
  const u16* p1 = vT + ((size_t)b * 512 + c1) * 4096;
#pragma unroll
  for (int it = 0; it < 16; it++) {
    const int j = t + (it << 9);
    float a = 0.f, bb = 0.f;
    if (j < 4096) { a = b2f(p0[j]); bb = b2f(p1[j]); }
    S[SWZ(brev13(j))] = dn2(a, bb);
  }
  fft8192_dit_h2(S, tw);
  const float2* A0 = aspec + (size_t)c0 * 4097;
  const float2* A1 = aspec + (size_t)c1 * 4097;
#pragma unroll 1
  for (int it = 0; it < 8; it++) {
    mulpoint_h2(S, A0, A1, t + (it << 9));
  }
  if (t == 0) mulpoint_h2(S, A0, A1, 4096);
  ifft8192_dif_h2(S, tw);
  u16* o0 = outT + ((size_t)b * 512 + c0) * 4096;
  u16* o1 = outT + ((size_t)b * 512 + c1) * 4096;
#pragma unroll
  for (int it = 0; it < 8; it++) {
    const int i = t + (it << 9);
    const float2 v = up2(S[SWZ(brev13(i))]);
    o0[i] = f2b(v.x);
    o1[i] = f2b(v.y);
  }
}

// ---------------------------------------------------------------------------
extern "C" void kernel_launch(void* const* d_in, const int* in_sizes, int n_in,
                              void* d_out, int out_size, void* d_ws, size_t ws_size,
                              hipStream_t stream)
{
  const float* x   = (const float*)d_in[0];
  const float* Wu  = (const float*)d_in[1];
  const float* bu  = (const float*)d_in[2];
  const float* Wv  = (const float*)d_in[3];
  const float* bv  = (const float*)d_in[4];
  const float* Wo1 = (const float*)d_in[5];
  const float* bo1 = (const float*)d_in[6];
  const float* Wo2 = (const float*)d_in[7];
  const float* bo2 = (const float*)d_in[8];
  const float* dWp = (const float*)d_in[9];
  const float* dbp = (const float*)d_in[10];
  const float* dW1 = (const float*)d_in[11];
  const float* db1 = (const float*)d_in[12];
  const float* dW2 = (const float*)d_in[13];
  const float* db2 = (const float*)d_in[14];
  const float* dW3 = (const float*)d_in[15];
  const float* db3 = (const float*)d_in[16];
  float* out = (float*)d_out;

  char* wsb = (char*)d_ws;
  const size_t MB = 1u << 20;
  // bf16 weight pool @ 0-6 MB
  u16* WuT  = (u16*)wsb;                    // 1024x512
  u16* WvT  = WuT + 524288;                 // 512x512
  u16* Wo1T = WvT + 262144;                 // 1024x512
  u16* Wo2T = Wo1T + 524288;                // 512x1024
  u16* dW1T = Wo2T + 524288;                // 512x512
  u16* dW2T = dW1T + 262144;
  u16* dW3T = dW2T + 262144;
  // activations / scratch
  u16*    XNb   = (u16*)(wsb + 6 * MB);     // 32768x512 bf16 (dies after u/v)
  u16*    D0b   = (u16*)(wsb + 6 * MB);     // 8192x512 bf16 (over dead XNb)
  float*  D1    = (float*)(wsb + 14 * MB);  // 8192x512 fp32 (DPB hidden layers)
  float*  D1T   = (float*)(wsb + 14 * MB);  // 512x8192 fp32 (final DPB, transposed)
  u16*    CT    = (u16*)(wsb + 6 * MB);     // (8,512,4096) bf16 (after kfft)
  u16*    G     = (u16*)(wsb + 6 * MB);     // 32768x1024 bf16 (after transpose)
  u16*    VTb   = (u16*)(wsb + 38 * MB);    // (8,512,4096) bf16 (dies after conv)
  float2* ASPEC = (float2*)(wsb + 70 * MB); // 512x4097 c64 (~16.8MB)
  float2* TW    = (float2*)(wsb + 87 * MB); // 4096 c64
  u16*    CR    = (u16*)(wsb + 88 * MB);    // 32768x512 bf16
  u16*    U     = (u16*)(wsb + 128 * MB);   // 32768x1024 bf16

  dim3 wt_blk(32, 8);
  // weight transposes + casts
  wtrans_kernel<<<dim3(32, 16), wt_blk, 0, stream>>>(Wu, WuT, 512, 1024);
  wtrans_kernel<<<dim3(16, 16), wt_blk, 0, stream>>>(Wv, WvT, 512, 512);
  wtrans_kernel<<<dim3(32, 16), wt_blk, 0, stream>>>(Wo1, Wo1T, 512, 1024);
  wtrans_kernel<<<dim3(16, 32), wt_blk, 0, stream>>>(Wo2, Wo2T, 1024, 512);
  wtrans_kernel<<<dim3(16, 16), wt_blk, 0, stream>>>(dW1, dW1T, 512, 512);
  wtrans_kernel<<<dim3(16, 16), wt_blk, 0, stream>>>(dW2, dW2T, 512, 512);
  wtrans_kernel<<<dim3(16, 16), wt_blk, 0, stream>>>(dW3, dW3T, 512, 512);
  twiddle_init_kernel<<<8, 512, 0, stream>>>(TW);

  // pre-norm -> bf16
  srms_bf16_kernel<<<8192, 256, 0, stream>>>(x, XNb, 32768, 0);
  // v = silu(xn@Wv+bv) -> VTb channel-major bf16 (fused transpose)
  gemm_bf16_kernel<2><<<dim3(4, 256), 256, 0, stream>>>(XNb, WvT, bv, nullptr, nullptr, VTb, 32768, 512, 512);
  // u = silu(xn@Wu+bu) -> U bf16
  gemm_bf16_kernel<1><<<dim3(8, 256), 256, 0, stream>>>(XNb, WuT, bu, nullptr, nullptr, U, 32768, 1024, 512);

  // DPB MLP -> transposed circulant table D1T (512, 8192) fp32
  dpb0_kernel<<<2048, 256, 0, stream>>>(dWp, dbp, D0b);
  gemm_bf16_kernel<0><<<dim3(4, 64), 256, 0, stream>>>(D0b, dW1T, db1, nullptr, nullptr, D1, 8192, 512, 512);
  srms_bf16_kernel<<<2048, 256, 0, stream>>>(D1, D0b, 8192, 1);
  gemm_bf16_kernel<0><<<dim3(4, 64), 256, 0, stream>>>(D0b, dW2T, db2, nullptr, nullptr, D1, 8192, 512, 512);
  srms_bf16_kernel<<<2048, 256, 0, stream>>>(D1, D0b, 8192, 1);
  gemm_bf16_kernel<5><<<dim3(4, 64), 256, 0, stream>>>(D0b, dW3T, db3, nullptr, nullptr, D1T, 8192, 512, 512);
  // kernel spectra (coalesced rows of D1T), pre-scaled by 1/8192
  kfft_kernel<<<256, 512, 0, stream>>>(D1T, TW, ASPEC);
  // FFT conv: VTb -> CT (bf16, channel-major)
  conv_kernel<<<dim3(256, 8), 512, 0, stream>>>(VTb, ASPEC, TW, CT);
  // CT -> CR row-major bf16
  transpose_b16_kernel<<<dim3(128, 16, 8), wt_blk, 0, stream>>>(CT, CR);
  // gate: (CR@Wo1+bo1)*U -> G bf16
  gemm_bf16_kernel<3><<<dim3(8, 256), 256, 0, stream>>>(CR, Wo1T, bo1, U, nullptr, G, 32768, 1024, 512);
  // final: G@Wo2 + bo2 + x -> out fp32
  gemm_bf16_kernel<4><<<dim3(4, 256), 256, 0, stream>>>(G, Wo2T, bo2, nullptr, x, out, 32768, 512, 1024);
}